// Round 1
// baseline (1060.800 us; speedup 1.0000x reference)
//
#include <hip/hip_runtime.h>
#include <hip/hip_bf16.h>

// ---------------------------------------------------------------------------
// GATv2 (2 conv layers + GraphNorm + 3-layer MLP) on MI355X, fp32 baseline.
// N=50000 nodes, E=800000 edges (+N self loops), H=4 heads, C=64, HC=256.
// ---------------------------------------------------------------------------

__device__ __forceinline__ float wave_sum64(float v) {
    v += __shfl_xor(v, 32);
    v += __shfl_xor(v, 16);
    v += __shfl_xor(v, 8);
    v += __shfl_xor(v, 4);
    v += __shfl_xor(v, 2);
    v += __shfl_xor(v, 1);
    return v;
}

// ------------------------- generic tiled fp32 GEMM -------------------------
// C[M,N] = act(A[M,K] @ W[K,N] + bias[N]);  K % 32 == 0, N % 64 == 0.
__global__ __launch_bounds__(256) void gemm_bias_act(
    const float* __restrict__ A, const float* __restrict__ W,
    const float* __restrict__ bias, float* __restrict__ C,
    int M, int N, int K, int act)
{
    __shared__ float As[32][68];   // A tile transposed: As[k][m]
    __shared__ float Ws[32][68];   // W tile: Ws[k][n]
    const int tid = threadIdx.x;
    const int bm = blockIdx.x * 64;
    const int bn = blockIdx.y * 64;
    const int tx = tid & 15, ty = tid >> 4;
    float acc[4][4] = {{0.f, 0.f, 0.f, 0.f}};

    for (int k0 = 0; k0 < K; k0 += 32) {
        // load A tile: 64 rows x 32 k, 512 float4, 2 per thread (transpose into LDS)
        #pragma unroll
        for (int i = 0; i < 2; ++i) {
            int idx = tid + i * 256;
            int row = idx >> 3;
            int col4 = (idx & 7) * 4;
            int grow = bm + row;
            float4 v = make_float4(0.f, 0.f, 0.f, 0.f);
            if (grow < M) v = *(const float4*)(A + (size_t)grow * K + k0 + col4);
            As[col4 + 0][row] = v.x;
            As[col4 + 1][row] = v.y;
            As[col4 + 2][row] = v.z;
            As[col4 + 3][row] = v.w;
        }
        // load W tile: 32 k x 64 n
        #pragma unroll
        for (int i = 0; i < 2; ++i) {
            int idx = tid + i * 256;
            int row = idx >> 4;
            int col4 = (idx & 15) * 4;
            float4 v = *(const float4*)(W + (size_t)(k0 + row) * N + bn + col4);
            *(float4*)&Ws[row][col4] = v;
        }
        __syncthreads();
        #pragma unroll
        for (int kk = 0; kk < 32; ++kk) {
            float4 av = *(const float4*)&As[kk][ty * 4];
            float4 bv = *(const float4*)&Ws[kk][tx * 4];
            float a4[4] = {av.x, av.y, av.z, av.w};
            float b4[4] = {bv.x, bv.y, bv.z, bv.w};
            #pragma unroll
            for (int i = 0; i < 4; ++i)
                #pragma unroll
                for (int j = 0; j < 4; ++j)
                    acc[i][j] = fmaf(a4[i], b4[j], acc[i][j]);
        }
        __syncthreads();
    }

    #pragma unroll
    for (int i = 0; i < 4; ++i) {
        int row = bm + ty * 4 + i;
        if (row >= M) continue;
        #pragma unroll
        for (int j = 0; j < 4; ++j) {
            int col = bn + tx * 4 + j;
            float v = acc[i][j] + bias[col];
            if (act) v = fmaxf(v, 0.f);
            C[(size_t)row * N + col] = v;
        }
    }
}

// ----------------------------- CSR build (by dst) --------------------------
__global__ void zero_i32(int* __restrict__ p, int n) {
    int i = blockIdx.x * 256 + threadIdx.x;
    if (i < n) p[i] = 0;
}
__global__ void zero_f32(float* __restrict__ p, int n) {
    int i = blockIdx.x * 256 + threadIdx.x;
    if (i < n) p[i] = 0.f;
}
__global__ void hist_kernel(const int* __restrict__ dst, int E, int* __restrict__ hist) {
    int e = blockIdx.x * 256 + threadIdx.x;
    if (e < E) atomicAdd(&hist[dst[e]], 1);
}
__global__ __launch_bounds__(1024) void scan_kernel(
    const int* __restrict__ hist, int* __restrict__ row_ptr,
    int* __restrict__ cursor, int n)
{
    __shared__ int sums[1024];
    int tid = threadIdx.x;
    int chunk = (n + 1023) >> 10;
    int lo = tid * chunk;
    int hi = min(n, lo + chunk);
    int s = 0;
    for (int i = lo; i < hi; ++i) s += hist[i];
    sums[tid] = s;
    __syncthreads();
    for (int off = 1; off < 1024; off <<= 1) {
        int v = (tid >= off) ? sums[tid - off] : 0;
        __syncthreads();
        sums[tid] += v;
        __syncthreads();
    }
    int run = (tid > 0) ? sums[tid - 1] : 0;
    for (int i = lo; i < hi; ++i) {
        row_ptr[i] = run;
        cursor[i] = run;
        run += hist[i];
    }
    if (tid == 1023) row_ptr[n] = sums[1023];
}
__global__ void scatter_kernel(const int* __restrict__ src, const int* __restrict__ dst,
                               int E, int* cursor, int* __restrict__ esrc)
{
    int e = blockIdx.x * 256 + threadIdx.x;
    if (e < E) {
        int pos = atomicAdd(&cursor[dst[e]], 1);
        esrc[pos] = src[e];
    }
}

// --------------------- fused GATv2 softmax + aggregation -------------------
// One block per node; wave h (of 4) owns head h; lane = channel c in [0,64).
// Single pass over incoming edges with online softmax; self-loop first.
__global__ __launch_bounds__(256) void gat_aggregate(
    const float* __restrict__ xl, const float* __restrict__ xr,
    const float* __restrict__ att, const int* __restrict__ row_ptr,
    const int* __restrict__ esrc, const float* __restrict__ bias,
    float* __restrict__ out)
{
    const int node = blockIdx.x;
    const int h = threadIdx.x >> 6;
    const int lane = threadIdx.x & 63;
    const int col = h * 64 + lane;
    const float attv = att[col];
    const size_t nbase = (size_t)node * 256 + col;
    const float xrv = xr[nbase];

    // self loop
    float xlv_self = xl[nbase];
    float z = xlv_self + xrv;
    float e = wave_sum64(attv * (z > 0.f ? z : 0.2f * z));
    float m = e, s = 1.f, acc = xlv_self;

    int t = row_ptr[node];
    const int end = row_ptr[node + 1];
    int nsrc = (t < end) ? esrc[t] : 0;
    float nxl = (t < end) ? xl[(size_t)nsrc * 256 + col] : 0.f;
    while (t < end) {
        float xlv = nxl;
        ++t;
        if (t < end) {
            nsrc = esrc[t];
            nxl = xl[(size_t)nsrc * 256 + col];
        }
        z = xlv + xrv;
        e = wave_sum64(attv * (z > 0.f ? z : 0.2f * z));
        float mn = fmaxf(m, e);
        float sc = __expf(m - mn);
        float w = __expf(e - mn);
        s = fmaf(s, sc, w);
        acc = fmaf(acc, sc, w * xlv);
        m = mn;
    }
    out[nbase] = acc / (s + 1e-16f) + bias[col];
}

// ------------------------------- GraphNorm ---------------------------------
__global__ __launch_bounds__(256) void colstats(
    const float* __restrict__ x, int n,
    float* __restrict__ sum, float* __restrict__ sumsq)
{
    const int c = threadIdx.x;
    float s = 0.f, q = 0.f;
    for (int r = blockIdx.x; r < n; r += gridDim.x) {
        float v = x[(size_t)r * 256 + c];
        s += v;
        q = fmaf(v, v, q);
    }
    atomicAdd(&sum[c], s);
    atomicAdd(&sumsq[c], q);
}
__global__ void norm_finalize(const float* __restrict__ sum, const float* __restrict__ sumsq,
                              const float* __restrict__ w, const float* __restrict__ b,
                              const float* __restrict__ ms,
                              float* __restrict__ a, float* __restrict__ c2, float invn)
{
    int i = threadIdx.x;
    float mean = sum[i] * invn;
    float ex2 = sumsq[i] * invn;
    float m = ms[i];
    float var = ex2 - 2.f * m * mean * mean + m * m * mean * mean;
    float av = w[i] * rsqrtf(var + 1e-5f);
    a[i] = av;
    c2[i] = b[i] - av * m * mean;
}
__global__ void norm_apply(float* __restrict__ x, const float* __restrict__ a,
                           const float* __restrict__ c2, int n4)
{
    int i = blockIdx.x * 256 + threadIdx.x;
    if (i >= n4) return;
    float4 v = ((float4*)x)[i];
    int base = (i * 4) & 255;
    v.x = fmaxf(fmaf(a[base + 0], v.x, c2[base + 0]), 0.f);
    v.y = fmaxf(fmaf(a[base + 1], v.y, c2[base + 1]), 0.f);
    v.z = fmaxf(fmaf(a[base + 2], v.z, c2[base + 2]), 0.f);
    v.w = fmaxf(fmaf(a[base + 3], v.w, c2[base + 3]), 0.f);
    ((float4*)x)[i] = v;
}

// ---------------------------------- lin2 -----------------------------------
__global__ void lin2_kernel(const float* __restrict__ h, const float* __restrict__ w,
                            const float* __restrict__ b, float* __restrict__ out, int n)
{
    int i = blockIdx.x * 256 + threadIdx.x;
    if (i >= n) return;
    float a0 = b[0], a1 = b[1];
    const float* hr = h + (size_t)i * 64;
    #pragma unroll
    for (int k = 0; k < 64; ++k) {
        float v = hr[k];
        a0 = fmaf(v, w[k * 2 + 0], a0);
        a1 = fmaf(v, w[k * 2 + 1], a1);
    }
    out[i * 2 + 0] = a0;
    out[i * 2 + 1] = a1;
}

// ---------------------------------------------------------------------------
extern "C" void kernel_launch(void* const* d_in, const int* in_sizes, int n_in,
                              void* d_out, int out_size, void* d_ws, size_t ws_size,
                              hipStream_t stream)
{
    const float* x      = (const float*)d_in[0];
    const int*   eidx   = (const int*)d_in[1];
    const float* c0_wl  = (const float*)d_in[2];
    const float* c0_bl  = (const float*)d_in[3];
    const float* c0_wr  = (const float*)d_in[4];
    const float* c0_br  = (const float*)d_in[5];
    const float* c0_att = (const float*)d_in[6];
    const float* c0_bias= (const float*)d_in[7];
    const float* c1_wl  = (const float*)d_in[8];
    const float* c1_bl  = (const float*)d_in[9];
    const float* c1_wr  = (const float*)d_in[10];
    const float* c1_br  = (const float*)d_in[11];
    const float* c1_att = (const float*)d_in[12];
    const float* c1_bias= (const float*)d_in[13];
    const float* gn0_w  = (const float*)d_in[14];
    const float* gn0_b  = (const float*)d_in[15];
    const float* gn0_ms = (const float*)d_in[16];
    const float* gn1_w  = (const float*)d_in[17];
    const float* gn1_b  = (const float*)d_in[18];
    const float* gn1_ms = (const float*)d_in[19];
    const float* lin0_w = (const float*)d_in[20];
    const float* lin0_b = (const float*)d_in[21];
    const float* lin1_w = (const float*)d_in[22];
    const float* lin1_b = (const float*)d_in[23];
    const float* lin2_w = (const float*)d_in[24];
    const float* lin2_b = (const float*)d_in[25];

    const int n = in_sizes[0] / 128;   // 50000
    const int E = in_sizes[1] / 2;     // 800000
    const int* src = eidx;
    const int* dst = eidx + E;

    char* wsp = (char*)d_ws;
    size_t off = 0;
    auto alloc = [&](size_t bytes) -> void* {
        void* p = wsp + off;
        off = (off + bytes + 255) & ~(size_t)255;
        return p;
    };
    float* xl      = (float*)alloc((size_t)n * 256 * 4);
    float* xr      = (float*)alloc((size_t)n * 256 * 4);
    float* hb      = (float*)alloc((size_t)n * 256 * 4);
    int*   esrc    = (int*)alloc((size_t)E * 4);
    int*   row_ptr = (int*)alloc((size_t)(n + 1) * 4);
    int*   cursor  = (int*)alloc((size_t)n * 4);
    int*   hist    = (int*)alloc((size_t)n * 4);
    float* s_sum   = (float*)alloc(256 * 4);
    float* s_sq    = (float*)alloc(256 * 4);
    float* s_a     = (float*)alloc(256 * 4);
    float* s_c     = (float*)alloc(256 * 4);
    float* mbuf    = xl;   // reuse after conv phase
    float* mbuf2   = xr;

    // ---- CSR by dst (raw edges; self-loops handled in-kernel) ----
    zero_i32<<<(n + 255) / 256, 256, 0, stream>>>(hist, n);
    hist_kernel<<<(E + 255) / 256, 256, 0, stream>>>(dst, E, hist);
    scan_kernel<<<1, 1024, 0, stream>>>(hist, row_ptr, cursor, n);
    scatter_kernel<<<(E + 255) / 256, 256, 0, stream>>>(src, dst, E, cursor, esrc);

    dim3 gc((n + 63) / 64, 4);   // N=256
    dim3 gm((n + 63) / 64, 1);   // N=64

    // ---- conv0 ----
    gemm_bias_act<<<gc, 256, 0, stream>>>(x, c0_wl, c0_bl, xl, n, 256, 128, 0);
    gemm_bias_act<<<gc, 256, 0, stream>>>(x, c0_wr, c0_br, xr, n, 256, 128, 0);
    gat_aggregate<<<n, 256, 0, stream>>>(xl, xr, c0_att, row_ptr, esrc, c0_bias, hb);

    // ---- GraphNorm 0 + relu (in place) ----
    zero_f32<<<2, 256, 0, stream>>>(s_sum, 512);   // s_sum and s_sq are contiguous
    colstats<<<512, 256, 0, stream>>>(hb, n, s_sum, s_sq);
    norm_finalize<<<1, 256, 0, stream>>>(s_sum, s_sq, gn0_w, gn0_b, gn0_ms, s_a, s_c, 1.f / n);
    norm_apply<<<((n * 64) + 255) / 256, 256, 0, stream>>>(hb, s_a, s_c, n * 64);

    // ---- conv1 ----
    gemm_bias_act<<<gc, 256, 0, stream>>>(hb, c1_wl, c1_bl, xl, n, 256, 256, 0);
    gemm_bias_act<<<gc, 256, 0, stream>>>(hb, c1_wr, c1_br, xr, n, 256, 256, 0);
    gat_aggregate<<<n, 256, 0, stream>>>(xl, xr, c1_att, row_ptr, esrc, c1_bias, hb);

    // ---- GraphNorm 1 + relu (in place) ----
    zero_f32<<<2, 256, 0, stream>>>(s_sum, 512);
    colstats<<<512, 256, 0, stream>>>(hb, n, s_sum, s_sq);
    norm_finalize<<<1, 256, 0, stream>>>(s_sum, s_sq, gn1_w, gn1_b, gn1_ms, s_a, s_c, 1.f / n);
    norm_apply<<<((n * 64) + 255) / 256, 256, 0, stream>>>(hb, s_a, s_c, n * 64);

    // ---- MLP ----
    gemm_bias_act<<<gm, 256, 0, stream>>>(hb, lin0_w, lin0_b, mbuf, n, 64, 256, 1);
    gemm_bias_act<<<gm, 256, 0, stream>>>(mbuf, lin1_w, lin1_b, mbuf2, n, 64, 64, 1);
    lin2_kernel<<<(n + 255) / 256, 256, 0, stream>>>(mbuf2, lin2_w, lin2_b, (float*)d_out, n);
}

// Round 3
// 884.534 us; speedup vs baseline: 1.1993x; 1.1993x over previous
//
#include <hip/hip_runtime.h>
#include <hip/hip_bf16.h>

// ---------------------------------------------------------------------------
// GATv2 (2 conv layers + GraphNorm + 3-layer MLP) on MI355X, fp32.
// N=50000 nodes, E=800000 edges (+N self loops), H=4 heads, C=64, HC=256.
// Round 2: wave-per-node aggregation, 16-lane DPP row_ror reduction,
//          exp2-domain online softmax (__builtin_amdgcn_exp2f).
// ---------------------------------------------------------------------------

// ------------------------- generic tiled fp32 GEMM -------------------------
// C[M,N] = act(A[M,K] @ W[K,N] + bias[N]);  K % 32 == 0, N % 64 == 0.
__global__ __launch_bounds__(256) void gemm_bias_act(
    const float* __restrict__ A, const float* __restrict__ W,
    const float* __restrict__ bias, float* __restrict__ C,
    int M, int N, int K, int act)
{
    __shared__ float As[32][68];   // A tile transposed: As[k][m]
    __shared__ float Ws[32][68];   // W tile: Ws[k][n]
    const int tid = threadIdx.x;
    const int bm = blockIdx.x * 64;
    const int bn = blockIdx.y * 64;
    const int tx = tid & 15, ty = tid >> 4;
    float acc[4][4] = {{0.f, 0.f, 0.f, 0.f}};

    for (int k0 = 0; k0 < K; k0 += 32) {
        #pragma unroll
        for (int i = 0; i < 2; ++i) {
            int idx = tid + i * 256;
            int row = idx >> 3;
            int col4 = (idx & 7) * 4;
            int grow = bm + row;
            float4 v = make_float4(0.f, 0.f, 0.f, 0.f);
            if (grow < M) v = *(const float4*)(A + (size_t)grow * K + k0 + col4);
            As[col4 + 0][row] = v.x;
            As[col4 + 1][row] = v.y;
            As[col4 + 2][row] = v.z;
            As[col4 + 3][row] = v.w;
        }
        #pragma unroll
        for (int i = 0; i < 2; ++i) {
            int idx = tid + i * 256;
            int row = idx >> 4;
            int col4 = (idx & 15) * 4;
            float4 v = *(const float4*)(W + (size_t)(k0 + row) * N + bn + col4);
            *(float4*)&Ws[row][col4] = v;
        }
        __syncthreads();
        #pragma unroll
        for (int kk = 0; kk < 32; ++kk) {
            float4 av = *(const float4*)&As[kk][ty * 4];
            float4 bv = *(const float4*)&Ws[kk][tx * 4];
            float a4[4] = {av.x, av.y, av.z, av.w};
            float b4[4] = {bv.x, bv.y, bv.z, bv.w};
            #pragma unroll
            for (int i = 0; i < 4; ++i)
                #pragma unroll
                for (int j = 0; j < 4; ++j)
                    acc[i][j] = fmaf(a4[i], b4[j], acc[i][j]);
        }
        __syncthreads();
    }

    #pragma unroll
    for (int i = 0; i < 4; ++i) {
        int row = bm + ty * 4 + i;
        if (row >= M) continue;
        #pragma unroll
        for (int j = 0; j < 4; ++j) {
            int col = bn + tx * 4 + j;
            float v = acc[i][j] + bias[col];
            if (act) v = fmaxf(v, 0.f);
            C[(size_t)row * N + col] = v;
        }
    }
}

// ----------------------------- CSR build (by dst) --------------------------
__global__ void zero_i32(int* __restrict__ p, int n) {
    int i = blockIdx.x * 256 + threadIdx.x;
    if (i < n) p[i] = 0;
}
__global__ void zero_f32(float* __restrict__ p, int n) {
    int i = blockIdx.x * 256 + threadIdx.x;
    if (i < n) p[i] = 0.f;
}
__global__ void hist_kernel(const int* __restrict__ dst, int E, int* __restrict__ hist) {
    int e = blockIdx.x * 256 + threadIdx.x;
    if (e < E) atomicAdd(&hist[dst[e]], 1);
}
__global__ __launch_bounds__(1024) void scan_kernel(
    const int* __restrict__ hist, int* __restrict__ row_ptr,
    int* __restrict__ cursor, int n)
{
    __shared__ int sums[1024];
    int tid = threadIdx.x;
    int chunk = (n + 1023) >> 10;
    int lo = tid * chunk;
    int hi = min(n, lo + chunk);
    int s = 0;
    for (int i = lo; i < hi; ++i) s += hist[i];
    sums[tid] = s;
    __syncthreads();
    for (int off = 1; off < 1024; off <<= 1) {
        int v = (tid >= off) ? sums[tid - off] : 0;
        __syncthreads();
        sums[tid] += v;
        __syncthreads();
    }
    int run = (tid > 0) ? sums[tid - 1] : 0;
    for (int i = lo; i < hi; ++i) {
        row_ptr[i] = run;
        cursor[i] = run;
        run += hist[i];
    }
    if (tid == 1023) row_ptr[n] = sums[1023];
}
__global__ void scatter_kernel(const int* __restrict__ src, const int* __restrict__ dst,
                               int E, int* cursor, int* __restrict__ esrc)
{
    int e = blockIdx.x * 256 + threadIdx.x;
    if (e < E) {
        int pos = atomicAdd(&cursor[dst[e]], 1);
        esrc[pos] = src[e];
    }
}

// --------------------- fused GATv2 softmax + aggregation -------------------
// One WAVE per node (4 nodes per 256-thread block). Lane l owns channels
// [4l,4l+4): lanes 0-15 = head0 ... lanes 48-63 = head3. Per edge: one
// dwordx4 gather per lane, per-lane att-dot, 16-lane DPP row_ror reduce,
// online softmax (exp2 domain) per 16-lane group.

__device__ __forceinline__ float red16(float v) {
    // sum across each 16-lane DPP row via rotations 1,2,4,8
    v += __int_as_float(__builtin_amdgcn_update_dpp(0, __float_as_int(v), 0x121, 0xf, 0xf, true));
    v += __int_as_float(__builtin_amdgcn_update_dpp(0, __float_as_int(v), 0x122, 0xf, 0xf, true));
    v += __int_as_float(__builtin_amdgcn_update_dpp(0, __float_as_int(v), 0x124, 0xf, 0xf, true));
    v += __int_as_float(__builtin_amdgcn_update_dpp(0, __float_as_int(v), 0x128, 0xf, 0xf, true));
    return v;
}

__device__ __forceinline__ float att_dot(float4 v, float4 xr4, float4 a1, float4 a2) {
    float e = 0.f, z;
    z = v.x + xr4.x; e = fmaf(z > 0.f ? a1.x : a2.x, z, e);
    z = v.y + xr4.y; e = fmaf(z > 0.f ? a1.y : a2.y, z, e);
    z = v.z + xr4.z; e = fmaf(z > 0.f ? a1.z : a2.z, z, e);
    z = v.w + xr4.w; e = fmaf(z > 0.f ? a1.w : a2.w, z, e);
    return e;
}

__global__ __launch_bounds__(256) void gat_aggregate(
    const float* __restrict__ xl, const float* __restrict__ xr,
    const float* __restrict__ att, const int* __restrict__ row_ptr,
    const int* __restrict__ esrc, const float* __restrict__ bias,
    float* __restrict__ out, int n)
{
    const int lane = threadIdx.x & 63;
    const int node = __builtin_amdgcn_readfirstlane(blockIdx.x * 4 + (threadIdx.x >> 6));
    if (node >= n) return;
    const int c4 = lane * 4;

    const float LOG2E = 1.4426950408889634f;
    float4 a1 = *(const float4*)(att + c4);
    a1.x *= LOG2E; a1.y *= LOG2E; a1.z *= LOG2E; a1.w *= LOG2E;
    float4 a2 = make_float4(0.2f * a1.x, 0.2f * a1.y, 0.2f * a1.z, 0.2f * a1.w);
    const float4 xr4 = *(const float4*)(xr + (size_t)node * 256 + c4);

    // self loop first
    float4 xv = *(const float4*)(xl + (size_t)node * 256 + c4);
    float m = red16(att_dot(xv, xr4, a1, a2));
    float s = 1.f;
    float4 acc = xv;

    int t = row_ptr[node];
    const int end = row_ptr[node + 1];
    float4 nx;
    if (t < end) nx = *(const float4*)(xl + (size_t)esrc[t] * 256 + c4);
    while (t < end) {
        float4 v = nx;
        ++t;
        if (t < end) nx = *(const float4*)(xl + (size_t)esrc[t] * 256 + c4);
        float e = red16(att_dot(v, xr4, a1, a2));
        float mn = fmaxf(m, e);
        float cs = __builtin_amdgcn_exp2f(m - mn);
        float w  = __builtin_amdgcn_exp2f(e - mn);
        s = fmaf(s, cs, w);
        acc.x = fmaf(acc.x, cs, w * v.x);
        acc.y = fmaf(acc.y, cs, w * v.y);
        acc.z = fmaf(acc.z, cs, w * v.z);
        acc.w = fmaf(acc.w, cs, w * v.w);
        m = mn;
    }

    const float inv = 1.f / (s + 1e-16f);
    float4 b4 = *(const float4*)(bias + c4);
    float4 o;
    o.x = fmaf(acc.x, inv, b4.x);
    o.y = fmaf(acc.y, inv, b4.y);
    o.z = fmaf(acc.z, inv, b4.z);
    o.w = fmaf(acc.w, inv, b4.w);
    *(float4*)(out + (size_t)node * 256 + c4) = o;
}

// ------------------------------- GraphNorm ---------------------------------
__global__ __launch_bounds__(256) void colstats(
    const float* __restrict__ x, int n,
    float* __restrict__ sum, float* __restrict__ sumsq)
{
    const int c = threadIdx.x;
    float s = 0.f, q = 0.f;
    for (int r = blockIdx.x; r < n; r += gridDim.x) {
        float v = x[(size_t)r * 256 + c];
        s += v;
        q = fmaf(v, v, q);
    }
    atomicAdd(&sum[c], s);
    atomicAdd(&sumsq[c], q);
}
__global__ void norm_finalize(const float* __restrict__ sum, const float* __restrict__ sumsq,
                              const float* __restrict__ w, const float* __restrict__ b,
                              const float* __restrict__ ms,
                              float* __restrict__ a, float* __restrict__ c2, float invn)
{
    int i = threadIdx.x;
    float mean = sum[i] * invn;
    float ex2 = sumsq[i] * invn;
    float m = ms[i];
    float var = ex2 - 2.f * m * mean * mean + m * m * mean * mean;
    float av = w[i] * rsqrtf(var + 1e-5f);
    a[i] = av;
    c2[i] = b[i] - av * m * mean;
}
__global__ void norm_apply(float* __restrict__ x, const float* __restrict__ a,
                           const float* __restrict__ c2, int n4)
{
    int i = blockIdx.x * 256 + threadIdx.x;
    if (i >= n4) return;
    float4 v = ((float4*)x)[i];
    int base = (i * 4) & 255;
    v.x = fmaxf(fmaf(a[base + 0], v.x, c2[base + 0]), 0.f);
    v.y = fmaxf(fmaf(a[base + 1], v.y, c2[base + 1]), 0.f);
    v.z = fmaxf(fmaf(a[base + 2], v.z, c2[base + 2]), 0.f);
    v.w = fmaxf(fmaf(a[base + 3], v.w, c2[base + 3]), 0.f);
    ((float4*)x)[i] = v;
}

// ---------------------------------- lin2 -----------------------------------
__global__ void lin2_kernel(const float* __restrict__ h, const float* __restrict__ w,
                            const float* __restrict__ b, float* __restrict__ out, int n)
{
    int i = blockIdx.x * 256 + threadIdx.x;
    if (i >= n) return;
    float a0 = b[0], a1 = b[1];
    const float* hr = h + (size_t)i * 64;
    #pragma unroll
    for (int k = 0; k < 64; ++k) {
        float v = hr[k];
        a0 = fmaf(v, w[k * 2 + 0], a0);
        a1 = fmaf(v, w[k * 2 + 1], a1);
    }
    out[i * 2 + 0] = a0;
    out[i * 2 + 1] = a1;
}

// ---------------------------------------------------------------------------
extern "C" void kernel_launch(void* const* d_in, const int* in_sizes, int n_in,
                              void* d_out, int out_size, void* d_ws, size_t ws_size,
                              hipStream_t stream)
{
    const float* x      = (const float*)d_in[0];
    const int*   eidx   = (const int*)d_in[1];
    const float* c0_wl  = (const float*)d_in[2];
    const float* c0_bl  = (const float*)d_in[3];
    const float* c0_wr  = (const float*)d_in[4];
    const float* c0_br  = (const float*)d_in[5];
    const float* c0_att = (const float*)d_in[6];
    const float* c0_bias= (const float*)d_in[7];
    const float* c1_wl  = (const float*)d_in[8];
    const float* c1_bl  = (const float*)d_in[9];
    const float* c1_wr  = (const float*)d_in[10];
    const float* c1_br  = (const float*)d_in[11];
    const float* c1_att = (const float*)d_in[12];
    const float* c1_bias= (const float*)d_in[13];
    const float* gn0_w  = (const float*)d_in[14];
    const float* gn0_b  = (const float*)d_in[15];
    const float* gn0_ms = (const float*)d_in[16];
    const float* gn1_w  = (const float*)d_in[17];
    const float* gn1_b  = (const float*)d_in[18];
    const float* gn1_ms = (const float*)d_in[19];
    const float* lin0_w = (const float*)d_in[20];
    const float* lin0_b = (const float*)d_in[21];
    const float* lin1_w = (const float*)d_in[22];
    const float* lin1_b = (const float*)d_in[23];
    const float* lin2_w = (const float*)d_in[24];
    const float* lin2_b = (const float*)d_in[25];

    const int n = in_sizes[0] / 128;   // 50000
    const int E = in_sizes[1] / 2;     // 800000
    const int* src = eidx;
    const int* dst = eidx + E;

    char* wsp = (char*)d_ws;
    size_t off = 0;
    auto alloc = [&](size_t bytes) -> void* {
        void* p = wsp + off;
        off = (off + bytes + 255) & ~(size_t)255;
        return p;
    };
    float* xl      = (float*)alloc((size_t)n * 256 * 4);
    float* xr      = (float*)alloc((size_t)n * 256 * 4);
    float* hb      = (float*)alloc((size_t)n * 256 * 4);
    int*   esrc    = (int*)alloc((size_t)E * 4);
    int*   row_ptr = (int*)alloc((size_t)(n + 1) * 4);
    int*   cursor  = (int*)alloc((size_t)n * 4);
    int*   hist    = (int*)alloc((size_t)n * 4);
    float* s_sum   = (float*)alloc(256 * 4);
    float* s_sq    = (float*)alloc(256 * 4);
    float* s_a     = (float*)alloc(256 * 4);
    float* s_c     = (float*)alloc(256 * 4);
    float* mbuf    = xl;   // reuse after conv phase
    float* mbuf2   = xr;

    // ---- CSR by dst (raw edges; self-loops handled in-kernel) ----
    zero_i32<<<(n + 255) / 256, 256, 0, stream>>>(hist, n);
    hist_kernel<<<(E + 255) / 256, 256, 0, stream>>>(dst, E, hist);
    scan_kernel<<<1, 1024, 0, stream>>>(hist, row_ptr, cursor, n);
    scatter_kernel<<<(E + 255) / 256, 256, 0, stream>>>(src, dst, E, cursor, esrc);

    dim3 gc((n + 63) / 64, 4);   // N=256
    dim3 gm((n + 63) / 64, 1);   // N=64
    const int gagg = (n + 3) / 4;

    // ---- conv0 ----
    gemm_bias_act<<<gc, 256, 0, stream>>>(x, c0_wl, c0_bl, xl, n, 256, 128, 0);
    gemm_bias_act<<<gc, 256, 0, stream>>>(x, c0_wr, c0_br, xr, n, 256, 128, 0);
    gat_aggregate<<<gagg, 256, 0, stream>>>(xl, xr, c0_att, row_ptr, esrc, c0_bias, hb, n);

    // ---- GraphNorm 0 + relu (in place) ----
    zero_f32<<<2, 256, 0, stream>>>(s_sum, 512);   // s_sum and s_sq contiguous
    colstats<<<512, 256, 0, stream>>>(hb, n, s_sum, s_sq);
    norm_finalize<<<1, 256, 0, stream>>>(s_sum, s_sq, gn0_w, gn0_b, gn0_ms, s_a, s_c, 1.f / n);
    norm_apply<<<((n * 64) + 255) / 256, 256, 0, stream>>>(hb, s_a, s_c, n * 64);

    // ---- conv1 ----
    gemm_bias_act<<<gc, 256, 0, stream>>>(hb, c1_wl, c1_bl, xl, n, 256, 256, 0);
    gemm_bias_act<<<gc, 256, 0, stream>>>(hb, c1_wr, c1_br, xr, n, 256, 256, 0);
    gat_aggregate<<<gagg, 256, 0, stream>>>(xl, xr, c1_att, row_ptr, esrc, c1_bias, hb, n);

    // ---- GraphNorm 1 + relu (in place) ----
    zero_f32<<<2, 256, 0, stream>>>(s_sum, 512);
    colstats<<<512, 256, 0, stream>>>(hb, n, s_sum, s_sq);
    norm_finalize<<<1, 256, 0, stream>>>(s_sum, s_sq, gn1_w, gn1_b, gn1_ms, s_a, s_c, 1.f / n);
    norm_apply<<<((n * 64) + 255) / 256, 256, 0, stream>>>(hb, s_a, s_c, n * 64);

    // ---- MLP ----
    gemm_bias_act<<<gm, 256, 0, stream>>>(hb, lin0_w, lin0_b, mbuf, n, 64, 256, 1);
    gemm_bias_act<<<gm, 256, 0, stream>>>(mbuf, lin1_w, lin1_b, mbuf2, n, 64, 64, 1);
    lin2_kernel<<<(n + 255) / 256, 256, 0, stream>>>(mbuf2, lin2_w, lin2_b, (float*)d_out, n);
}

// Round 4
// 620.168 us; speedup vs baseline: 1.7105x; 1.4263x over previous
//
#include <hip/hip_runtime.h>
#include <hip/hip_bf16.h>

// ---------------------------------------------------------------------------
// GATv2 (2 conv + GraphNorm + MLP) on MI355X.
// Round 4: bf16 MFMA GEMMs (weights pre-transposed, fragments loaded straight
// from global, fused wl|wr), bf16 activation storage (halves gather bytes),
// fp32 softmax/accum. Aggregate structure unchanged from round 3.
// ---------------------------------------------------------------------------

typedef __bf16 bf16x8 __attribute__((ext_vector_type(8)));
typedef float  f32x4  __attribute__((ext_vector_type(4)));

__device__ __forceinline__ unsigned short f2b(float f) {   // RNE f32->bf16
    unsigned u = __float_as_uint(f);
    return (unsigned short)((u + 0x7fffu + ((u >> 16) & 1u)) >> 16);
}
__device__ __forceinline__ float4 b2f4(ushort4 u) {        // exact bf16->f32
    float4 f;
    f.x = __uint_as_float(((unsigned)u.x) << 16);
    f.y = __uint_as_float(((unsigned)u.y) << 16);
    f.z = __uint_as_float(((unsigned)u.z) << 16);
    f.w = __uint_as_float(((unsigned)u.w) << 16);
    return f;
}

// ----------------------------- prep kernels --------------------------------
__global__ void cast_bf16(const float* __restrict__ src, unsigned short* __restrict__ dst, int n4) {
    int i = blockIdx.x * 256 + threadIdx.x;
    if (i >= n4) return;
    float4 v = ((const float4*)src)[i];
    ushort4 o = { f2b(v.x), f2b(v.y), f2b(v.z), f2b(v.w) };
    ((ushort4*)dst)[i] = o;
}
// dst[n*K+k] = bf16(src[k*N+n])   (weight transpose+cast; tiny matrices)
__global__ void transpose_cast(const float* __restrict__ src, unsigned short* __restrict__ dst,
                               int K, int N) {
    int i = blockIdx.x * 256 + threadIdx.x;
    if (i >= K * N) return;
    int nn = i / K, kk = i - nn * K;
    dst[i] = f2b(src[(size_t)kk * N + nn]);
}

// ----------------------------- MFMA GEMM -----------------------------------
// C[M,N](bf16) = act(A[M,K](bf16) @ Bt[N,K]^T(bf16) + bias); K%32==0, N%64==0.
// Block: 4 waves, tile 128(M)x64(N); wave w owns rows [w*32,w*32+32).
// Fragments loaded directly from global (no LDS): A rows and Bt rows are
// contiguous-K, 16B per lane. Grid: (N/64, ceil(M/128)) so consecutive
// blocks share the A-tile via L2.
template<bool RELU>
__global__ __launch_bounds__(256) void mfma_gemm(
    const unsigned short* __restrict__ A, const unsigned short* __restrict__ Bt,
    const float* __restrict__ bias0, const float* __restrict__ bias1, int split,
    unsigned short* __restrict__ C, int M, int N, int K)
{
    const int lane = threadIdx.x & 63;
    const int w = threadIdx.x >> 6;
    const int bm = blockIdx.y * 128 + w * 32;
    const int bn = blockIdx.x * 64;
    const int lr = lane & 15;
    const int lk = (lane >> 4) * 8;

    f32x4 acc[2][4] = {};
    int r0 = bm + lr;      if (r0 >= M) r0 = M - 1;
    int r1 = bm + 16 + lr; if (r1 >= M) r1 = M - 1;
    const unsigned short* pa0 = A + (size_t)r0 * K + lk;
    const unsigned short* pa1 = A + (size_t)r1 * K + lk;
    const unsigned short* pb  = Bt + (size_t)(bn + lr) * K + lk;

    for (int k0 = 0; k0 < K; k0 += 32) {
        bf16x8 a0 = *(const bf16x8*)(pa0 + k0);
        bf16x8 a1 = *(const bf16x8*)(pa1 + k0);
        #pragma unroll
        for (int ni = 0; ni < 4; ++ni) {
            bf16x8 b = *(const bf16x8*)(pb + (size_t)ni * 16 * K + k0);
            acc[0][ni] = __builtin_amdgcn_mfma_f32_16x16x32_bf16(a0, b, acc[0][ni], 0, 0, 0);
            acc[1][ni] = __builtin_amdgcn_mfma_f32_16x16x32_bf16(a1, b, acc[1][ni], 0, 0, 0);
        }
    }

    const int orow = bm + (lane >> 4) * 4;
    const int ocol = bn + lr;
    #pragma unroll
    for (int ni = 0; ni < 4; ++ni) {
        int col = ocol + ni * 16;
        float bv = (col < split) ? bias0[col] : bias1[col - split];
        #pragma unroll
        for (int mi = 0; mi < 2; ++mi) {
            #pragma unroll
            for (int r = 0; r < 4; ++r) {
                int row = orow + mi * 16 + r;
                if (row < M) {
                    float v = acc[mi][ni][r] + bv;
                    if (RELU) v = fmaxf(v, 0.f);
                    C[(size_t)row * N + col] = f2b(v);
                }
            }
        }
    }
}

// ----------------------------- CSR build (by dst) --------------------------
__global__ void zero_i32(int* __restrict__ p, int n) {
    int i = blockIdx.x * 256 + threadIdx.x;
    if (i < n) p[i] = 0;
}
__global__ void zero_f32(float* __restrict__ p, int n) {
    int i = blockIdx.x * 256 + threadIdx.x;
    if (i < n) p[i] = 0.f;
}
__global__ void hist_kernel(const int* __restrict__ dst, int E, int* __restrict__ hist) {
    int e = blockIdx.x * 256 + threadIdx.x;
    if (e < E) atomicAdd(&hist[dst[e]], 1);
}
__global__ __launch_bounds__(1024) void scan_kernel(
    const int* __restrict__ hist, int* __restrict__ row_ptr,
    int* __restrict__ cursor, int n)
{
    __shared__ int sums[1024];
    int tid = threadIdx.x;
    int chunk = (n + 1023) >> 10;
    int lo = tid * chunk;
    int hi = min(n, lo + chunk);
    int s = 0;
    for (int i = lo; i < hi; ++i) s += hist[i];
    sums[tid] = s;
    __syncthreads();
    for (int off = 1; off < 1024; off <<= 1) {
        int v = (tid >= off) ? sums[tid - off] : 0;
        __syncthreads();
        sums[tid] += v;
        __syncthreads();
    }
    int run = (tid > 0) ? sums[tid - 1] : 0;
    for (int i = lo; i < hi; ++i) {
        row_ptr[i] = run;
        cursor[i] = run;
        run += hist[i];
    }
    if (tid == 1023) row_ptr[n] = sums[1023];
}
__global__ void scatter_kernel(const int* __restrict__ src, const int* __restrict__ dst,
                               int E, int* cursor, int* __restrict__ esrc)
{
    int e = blockIdx.x * 256 + threadIdx.x;
    if (e < E) {
        int pos = atomicAdd(&cursor[dst[e]], 1);
        esrc[pos] = src[e];
    }
}

// --------------------- fused GATv2 softmax + aggregation -------------------
// One wave per node; lane l owns channels [4l,4l+4); 16-lane DPP reduce;
// online softmax in exp2 domain. xlr is bf16 [node][512] = [xl | xr].
__device__ __forceinline__ float red16(float v) {
    v += __int_as_float(__builtin_amdgcn_update_dpp(0, __float_as_int(v), 0x121, 0xf, 0xf, true));
    v += __int_as_float(__builtin_amdgcn_update_dpp(0, __float_as_int(v), 0x122, 0xf, 0xf, true));
    v += __int_as_float(__builtin_amdgcn_update_dpp(0, __float_as_int(v), 0x124, 0xf, 0xf, true));
    v += __int_as_float(__builtin_amdgcn_update_dpp(0, __float_as_int(v), 0x128, 0xf, 0xf, true));
    return v;
}
__device__ __forceinline__ float att_dot(float4 v, float4 xr4, float4 a1, float4 a2) {
    float e = 0.f, z;
    z = v.x + xr4.x; e = fmaf(z > 0.f ? a1.x : a2.x, z, e);
    z = v.y + xr4.y; e = fmaf(z > 0.f ? a1.y : a2.y, z, e);
    z = v.z + xr4.z; e = fmaf(z > 0.f ? a1.z : a2.z, z, e);
    z = v.w + xr4.w; e = fmaf(z > 0.f ? a1.w : a2.w, z, e);
    return e;
}

__global__ __launch_bounds__(256) void gat_aggregate(
    const unsigned short* __restrict__ xlr, const float* __restrict__ att,
    const int* __restrict__ row_ptr, const int* __restrict__ esrc,
    const float* __restrict__ bias, float* __restrict__ out, int n)
{
    const int lane = threadIdx.x & 63;
    const int node = __builtin_amdgcn_readfirstlane(blockIdx.x * 4 + (threadIdx.x >> 6));
    if (node >= n) return;
    const int c4 = lane * 4;

    const float LOG2E = 1.4426950408889634f;
    float4 a1 = *(const float4*)(att + c4);
    a1.x *= LOG2E; a1.y *= LOG2E; a1.z *= LOG2E; a1.w *= LOG2E;
    float4 a2 = make_float4(0.2f * a1.x, 0.2f * a1.y, 0.2f * a1.z, 0.2f * a1.w);
    const float4 xr4 = b2f4(*(const ushort4*)(xlr + (size_t)node * 512 + 256 + c4));

    // self loop first
    float4 xv = b2f4(*(const ushort4*)(xlr + (size_t)node * 512 + c4));
    float m = red16(att_dot(xv, xr4, a1, a2));
    float s = 1.f;
    float4 acc = xv;

    int t = row_ptr[node];
    const int end = row_ptr[node + 1];
    ushort4 nu;
    if (t < end) nu = *(const ushort4*)(xlr + (size_t)esrc[t] * 512 + c4);
    while (t < end) {
        float4 v = b2f4(nu);
        ++t;
        if (t < end) nu = *(const ushort4*)(xlr + (size_t)esrc[t] * 512 + c4);
        float e = red16(att_dot(v, xr4, a1, a2));
        float mn = fmaxf(m, e);
        float cs = __builtin_amdgcn_exp2f(m - mn);
        float w  = __builtin_amdgcn_exp2f(e - mn);
        s = fmaf(s, cs, w);
        acc.x = fmaf(acc.x, cs, w * v.x);
        acc.y = fmaf(acc.y, cs, w * v.y);
        acc.z = fmaf(acc.z, cs, w * v.z);
        acc.w = fmaf(acc.w, cs, w * v.w);
        m = mn;
    }

    const float inv = 1.f / (s + 1e-16f);
    float4 b4 = *(const float4*)(bias + c4);
    float4 o;
    o.x = fmaf(acc.x, inv, b4.x);
    o.y = fmaf(acc.y, inv, b4.y);
    o.z = fmaf(acc.z, inv, b4.z);
    o.w = fmaf(acc.w, inv, b4.w);
    *(float4*)(out + (size_t)node * 256 + c4) = o;
}

// ------------------------------- GraphNorm ---------------------------------
__global__ __launch_bounds__(256) void colstats(
    const float* __restrict__ x, int n,
    float* __restrict__ sum, float* __restrict__ sumsq)
{
    const int c = threadIdx.x;
    float s = 0.f, q = 0.f;
    for (int r = blockIdx.x; r < n; r += gridDim.x) {
        float v = x[(size_t)r * 256 + c];
        s += v;
        q = fmaf(v, v, q);
    }
    atomicAdd(&sum[c], s);
    atomicAdd(&sumsq[c], q);
}
__global__ void norm_finalize(const float* __restrict__ sum, const float* __restrict__ sumsq,
                              const float* __restrict__ w, const float* __restrict__ b,
                              const float* __restrict__ ms,
                              float* __restrict__ a, float* __restrict__ c2, float invn)
{
    int i = threadIdx.x;
    float mean = sum[i] * invn;
    float ex2 = sumsq[i] * invn;
    float m = ms[i];
    float var = ex2 - 2.f * m * mean * mean + m * m * mean * mean;
    float av = w[i] * rsqrtf(var + 1e-5f);
    a[i] = av;
    c2[i] = b[i] - av * m * mean;
}
// normalize + relu + cast to bf16 (GEMM input for the next stage)
__global__ void norm_apply_cast(const float* __restrict__ x, const float* __restrict__ a,
                                const float* __restrict__ c2,
                                unsigned short* __restrict__ out, int n4)
{
    int i = blockIdx.x * 256 + threadIdx.x;
    if (i >= n4) return;
    float4 v = ((const float4*)x)[i];
    int base = (i * 4) & 255;
    ushort4 o;
    o.x = f2b(fmaxf(fmaf(a[base + 0], v.x, c2[base + 0]), 0.f));
    o.y = f2b(fmaxf(fmaf(a[base + 1], v.y, c2[base + 1]), 0.f));
    o.z = f2b(fmaxf(fmaf(a[base + 2], v.z, c2[base + 2]), 0.f));
    o.w = f2b(fmaxf(fmaf(a[base + 3], v.w, c2[base + 3]), 0.f));
    ((ushort4*)out)[i] = o;
}

// ---------------------------------- lin2 -----------------------------------
__global__ void lin2_kernel(const unsigned short* __restrict__ h, const float* __restrict__ w,
                            const float* __restrict__ b, float* __restrict__ out, int n)
{
    int i = blockIdx.x * 256 + threadIdx.x;
    if (i >= n) return;
    float a0 = b[0], a1 = b[1];
    const unsigned short* hr = h + (size_t)i * 64;
    #pragma unroll
    for (int k = 0; k < 64; ++k) {
        float v = __uint_as_float(((unsigned)hr[k]) << 16);
        a0 = fmaf(v, w[k * 2 + 0], a0);
        a1 = fmaf(v, w[k * 2 + 1], a1);
    }
    out[i * 2 + 0] = a0;
    out[i * 2 + 1] = a1;
}

// ---------------------------------------------------------------------------
extern "C" void kernel_launch(void* const* d_in, const int* in_sizes, int n_in,
                              void* d_out, int out_size, void* d_ws, size_t ws_size,
                              hipStream_t stream)
{
    const float* x      = (const float*)d_in[0];
    const int*   eidx   = (const int*)d_in[1];
    const float* c0_wl  = (const float*)d_in[2];
    const float* c0_bl  = (const float*)d_in[3];
    const float* c0_wr  = (const float*)d_in[4];
    const float* c0_br  = (const float*)d_in[5];
    const float* c0_att = (const float*)d_in[6];
    const float* c0_bias= (const float*)d_in[7];
    const float* c1_wl  = (const float*)d_in[8];
    const float* c1_bl  = (const float*)d_in[9];
    const float* c1_wr  = (const float*)d_in[10];
    const float* c1_br  = (const float*)d_in[11];
    const float* c1_att = (const float*)d_in[12];
    const float* c1_bias= (const float*)d_in[13];
    const float* gn0_w  = (const float*)d_in[14];
    const float* gn0_b  = (const float*)d_in[15];
    const float* gn0_ms = (const float*)d_in[16];
    const float* gn1_w  = (const float*)d_in[17];
    const float* gn1_b  = (const float*)d_in[18];
    const float* gn1_ms = (const float*)d_in[19];
    const float* lin0_w = (const float*)d_in[20];
    const float* lin0_b = (const float*)d_in[21];
    const float* lin1_w = (const float*)d_in[22];
    const float* lin1_b = (const float*)d_in[23];
    const float* lin2_w = (const float*)d_in[24];
    const float* lin2_b = (const float*)d_in[25];

    const int n = in_sizes[0] / 128;   // 50000
    const int E = in_sizes[1] / 2;     // 800000
    const int* src = eidx;
    const int* dst = eidx + E;

    char* wsp = (char*)d_ws;
    size_t off = 0;
    auto alloc = [&](size_t bytes) -> void* {
        void* p = wsp + off;
        off = (off + bytes + 255) & ~(size_t)255;
        return p;
    };
    unsigned short* xbf  = (unsigned short*)alloc((size_t)n * 128 * 2);  // x bf16
    unsigned short* xlr  = (unsigned short*)alloc((size_t)n * 512 * 2);  // [xl|xr] bf16
    float*          hb   = (float*)alloc((size_t)n * 256 * 4);           // aggregate out fp32
    unsigned short* hbb  = (unsigned short*)alloc((size_t)n * 256 * 2);  // normed bf16
    unsigned short* mbuf = (unsigned short*)alloc((size_t)n * 64 * 2);
    unsigned short* mbuf2= (unsigned short*)alloc((size_t)n * 64 * 2);
    unsigned short* Wt0  = (unsigned short*)alloc((size_t)512 * 128 * 2);
    unsigned short* Wt1  = (unsigned short*)alloc((size_t)512 * 256 * 2);
    unsigned short* Lt0  = (unsigned short*)alloc((size_t)64 * 256 * 2);
    unsigned short* Lt1  = (unsigned short*)alloc((size_t)64 * 64 * 2);
    int*   esrc    = (int*)alloc((size_t)E * 4);
    int*   row_ptr = (int*)alloc((size_t)(n + 1) * 4);
    int*   cursor  = (int*)alloc((size_t)n * 4);
    int*   hist    = (int*)alloc((size_t)n * 4);
    float* s_sum   = (float*)alloc(256 * 4);
    float* s_sq    = (float*)alloc(256 * 4);
    float* s_a     = (float*)alloc(256 * 4);
    float* s_c     = (float*)alloc(256 * 4);

    // ---- prep: casts + weight transposes ----
    cast_bf16<<<(n * 128 / 4 + 255) / 256, 256, 0, stream>>>(x, xbf, n * 128 / 4);
    transpose_cast<<<(128 * 256 + 255) / 256, 256, 0, stream>>>(c0_wl, Wt0, 128, 256);
    transpose_cast<<<(128 * 256 + 255) / 256, 256, 0, stream>>>(c0_wr, Wt0 + 256 * 128, 128, 256);
    transpose_cast<<<(256 * 256 + 255) / 256, 256, 0, stream>>>(c1_wl, Wt1, 256, 256);
    transpose_cast<<<(256 * 256 + 255) / 256, 256, 0, stream>>>(c1_wr, Wt1 + 256 * 256, 256, 256);
    transpose_cast<<<(256 * 64 + 255) / 256, 256, 0, stream>>>(lin0_w, Lt0, 256, 64);
    transpose_cast<<<(64 * 64 + 255) / 256, 256, 0, stream>>>(lin1_w, Lt1, 64, 64);

    // ---- CSR by dst ----
    zero_i32<<<(n + 255) / 256, 256, 0, stream>>>(hist, n);
    hist_kernel<<<(E + 255) / 256, 256, 0, stream>>>(dst, E, hist);
    scan_kernel<<<1, 1024, 0, stream>>>(hist, row_ptr, cursor, n);
    scatter_kernel<<<(E + 255) / 256, 256, 0, stream>>>(src, dst, E, cursor, esrc);

    const int mt = (n + 127) / 128;
    const int gagg = (n + 3) / 4;

    // ---- conv0: fused [xl|xr] GEMM + aggregate + norm ----
    mfma_gemm<false><<<dim3(8, mt), 256, 0, stream>>>(xbf, Wt0, c0_bl, c0_br, 256, xlr, n, 512, 128);
    gat_aggregate<<<gagg, 256, 0, stream>>>(xlr, c0_att, row_ptr, esrc, c0_bias, hb, n);
    zero_f32<<<2, 256, 0, stream>>>(s_sum, 512);   // s_sum,s_sq contiguous
    colstats<<<512, 256, 0, stream>>>(hb, n, s_sum, s_sq);
    norm_finalize<<<1, 256, 0, stream>>>(s_sum, s_sq, gn0_w, gn0_b, gn0_ms, s_a, s_c, 1.f / n);
    norm_apply_cast<<<((n * 64) + 255) / 256, 256, 0, stream>>>(hb, s_a, s_c, hbb, n * 64);

    // ---- conv1 ----
    mfma_gemm<false><<<dim3(8, mt), 256, 0, stream>>>(hbb, Wt1, c1_bl, c1_br, 256, xlr, n, 512, 256);
    gat_aggregate<<<gagg, 256, 0, stream>>>(xlr, c1_att, row_ptr, esrc, c1_bias, hb, n);
    zero_f32<<<2, 256, 0, stream>>>(s_sum, 512);
    colstats<<<512, 256, 0, stream>>>(hb, n, s_sum, s_sq);
    norm_finalize<<<1, 256, 0, stream>>>(s_sum, s_sq, gn1_w, gn1_b, gn1_ms, s_a, s_c, 1.f / n);
    norm_apply_cast<<<((n * 64) + 255) / 256, 256, 0, stream>>>(hb, s_a, s_c, hbb, n * 64);

    // ---- MLP ----
    mfma_gemm<true><<<dim3(1, mt), 256, 0, stream>>>(hbb, Lt0, lin0_b, lin0_b, 64, mbuf, n, 64, 256);
    mfma_gemm<true><<<dim3(1, mt), 256, 0, stream>>>(mbuf, Lt1, lin1_b, lin1_b, 64, mbuf2, n, 64, 64);
    lin2_kernel<<<(n + 255) / 256, 256, 0, stream>>>(mbuf2, lin2_w, lin2_b, (float*)d_out, n);
}

// Round 5
// 534.800 us; speedup vs baseline: 1.9835x; 1.1596x over previous
//
#include <hip/hip_runtime.h>
#include <hip/hip_bf16.h>

// ---------------------------------------------------------------------------
// GATv2 (2 conv + GraphNorm + MLP) on MI355X.
// Round 5: replace single-block serial scan (110us, 1 CU) with 3-kernel
// parallel scan (~10us). Everything else unchanged from round 4.
// ---------------------------------------------------------------------------

typedef __bf16 bf16x8 __attribute__((ext_vector_type(8)));
typedef float  f32x4  __attribute__((ext_vector_type(4)));

__device__ __forceinline__ unsigned short f2b(float f) {   // RNE f32->bf16
    unsigned u = __float_as_uint(f);
    return (unsigned short)((u + 0x7fffu + ((u >> 16) & 1u)) >> 16);
}
__device__ __forceinline__ float4 b2f4(ushort4 u) {        // exact bf16->f32
    float4 f;
    f.x = __uint_as_float(((unsigned)u.x) << 16);
    f.y = __uint_as_float(((unsigned)u.y) << 16);
    f.z = __uint_as_float(((unsigned)u.z) << 16);
    f.w = __uint_as_float(((unsigned)u.w) << 16);
    return f;
}

// ----------------------------- prep kernels --------------------------------
__global__ void cast_bf16(const float* __restrict__ src, unsigned short* __restrict__ dst, int n4) {
    int i = blockIdx.x * 256 + threadIdx.x;
    if (i >= n4) return;
    float4 v = ((const float4*)src)[i];
    ushort4 o = { f2b(v.x), f2b(v.y), f2b(v.z), f2b(v.w) };
    ((ushort4*)dst)[i] = o;
}
// dst[n*K+k] = bf16(src[k*N+n])   (weight transpose+cast; tiny matrices)
__global__ void transpose_cast(const float* __restrict__ src, unsigned short* __restrict__ dst,
                               int K, int N) {
    int i = blockIdx.x * 256 + threadIdx.x;
    if (i >= K * N) return;
    int nn = i / K, kk = i - nn * K;
    dst[i] = f2b(src[(size_t)kk * N + nn]);
}

// ----------------------------- MFMA GEMM -----------------------------------
// C[M,N](bf16) = act(A[M,K](bf16) @ Bt[N,K]^T(bf16) + bias); K%32==0, N%64==0.
// Block: 4 waves, tile 128(M)x64(N); wave w owns rows [w*32,w*32+32).
template<bool RELU>
__global__ __launch_bounds__(256) void mfma_gemm(
    const unsigned short* __restrict__ A, const unsigned short* __restrict__ Bt,
    const float* __restrict__ bias0, const float* __restrict__ bias1, int split,
    unsigned short* __restrict__ C, int M, int N, int K)
{
    const int lane = threadIdx.x & 63;
    const int w = threadIdx.x >> 6;
    const int bm = blockIdx.y * 128 + w * 32;
    const int bn = blockIdx.x * 64;
    const int lr = lane & 15;
    const int lk = (lane >> 4) * 8;

    f32x4 acc[2][4] = {};
    int r0 = bm + lr;      if (r0 >= M) r0 = M - 1;
    int r1 = bm + 16 + lr; if (r1 >= M) r1 = M - 1;
    const unsigned short* pa0 = A + (size_t)r0 * K + lk;
    const unsigned short* pa1 = A + (size_t)r1 * K + lk;
    const unsigned short* pb  = Bt + (size_t)(bn + lr) * K + lk;

    for (int k0 = 0; k0 < K; k0 += 32) {
        bf16x8 a0 = *(const bf16x8*)(pa0 + k0);
        bf16x8 a1 = *(const bf16x8*)(pa1 + k0);
        #pragma unroll
        for (int ni = 0; ni < 4; ++ni) {
            bf16x8 b = *(const bf16x8*)(pb + (size_t)ni * 16 * K + k0);
            acc[0][ni] = __builtin_amdgcn_mfma_f32_16x16x32_bf16(a0, b, acc[0][ni], 0, 0, 0);
            acc[1][ni] = __builtin_amdgcn_mfma_f32_16x16x32_bf16(a1, b, acc[1][ni], 0, 0, 0);
        }
    }

    const int orow = bm + (lane >> 4) * 4;
    const int ocol = bn + lr;
    #pragma unroll
    for (int ni = 0; ni < 4; ++ni) {
        int col = ocol + ni * 16;
        float bv = (col < split) ? bias0[col] : bias1[col - split];
        #pragma unroll
        for (int mi = 0; mi < 2; ++mi) {
            #pragma unroll
            for (int r = 0; r < 4; ++r) {
                int row = orow + mi * 16 + r;
                if (row < M) {
                    float v = acc[mi][ni][r] + bv;
                    if (RELU) v = fmaxf(v, 0.f);
                    C[(size_t)row * N + col] = f2b(v);
                }
            }
        }
    }
}

// ----------------------------- CSR build (by dst) --------------------------
__global__ void zero_i32(int* __restrict__ p, int n) {
    int i = blockIdx.x * 256 + threadIdx.x;
    if (i < n) p[i] = 0;
}
__global__ void zero_f32(float* __restrict__ p, int n) {
    int i = blockIdx.x * 256 + threadIdx.x;
    if (i < n) p[i] = 0.f;
}
__global__ void hist_kernel(const int* __restrict__ dst, int E, int* __restrict__ hist) {
    int e = blockIdx.x * 256 + threadIdx.x;
    if (e < E) atomicAdd(&hist[dst[e]], 1);
}

// 3-phase parallel exclusive scan of hist[n] -> row_ptr[n+1] (+cursor copy)
__global__ void blk_sum_kernel(const int* __restrict__ hist, int n, int* __restrict__ bsum) {
    __shared__ int lds[256];
    int t = threadIdx.x;
    int i = blockIdx.x * 256 + t;
    lds[t] = (i < n) ? hist[i] : 0;
    __syncthreads();
    for (int off = 128; off > 0; off >>= 1) {
        if (t < off) lds[t] += lds[t + off];
        __syncthreads();
    }
    if (t == 0) bsum[blockIdx.x] = lds[0];
}
__global__ void bsum_scan_kernel(int* __restrict__ bsum, int nblk,
                                 int* __restrict__ row_ptr, int n) {
    __shared__ int lds[256];
    int t = threadIdx.x;
    int v = (t < nblk) ? bsum[t] : 0;
    lds[t] = v;
    __syncthreads();
    for (int off = 1; off < 256; off <<= 1) {
        int u = (t >= off) ? lds[t - off] : 0;
        __syncthreads();
        lds[t] += u;
        __syncthreads();
    }
    if (t < nblk) bsum[t] = lds[t] - v;        // exclusive block offset
    if (t == 255) row_ptr[n] = lds[255];       // grand total
}
__global__ void final_scan_kernel(const int* __restrict__ hist, const int* __restrict__ bsum,
                                  int n, int* __restrict__ row_ptr, int* __restrict__ cursor) {
    __shared__ int lds[256];
    int t = threadIdx.x;
    int i = blockIdx.x * 256 + t;
    int v = (i < n) ? hist[i] : 0;
    lds[t] = v;
    __syncthreads();
    for (int off = 1; off < 256; off <<= 1) {
        int u = (t >= off) ? lds[t - off] : 0;
        __syncthreads();
        lds[t] += u;
        __syncthreads();
    }
    if (i < n) {
        int ex = bsum[blockIdx.x] + lds[t] - v;
        row_ptr[i] = ex;
        cursor[i] = ex;
    }
}

__global__ void scatter_kernel(const int* __restrict__ src, const int* __restrict__ dst,
                               int E, int* cursor, int* __restrict__ esrc)
{
    int e = blockIdx.x * 256 + threadIdx.x;
    if (e < E) {
        int pos = atomicAdd(&cursor[dst[e]], 1);
        esrc[pos] = src[e];
    }
}

// --------------------- fused GATv2 softmax + aggregation -------------------
// One wave per node; lane l owns channels [4l,4l+4); 16-lane DPP reduce;
// online softmax in exp2 domain. xlr is bf16 [node][512] = [xl | xr].
__device__ __forceinline__ float red16(float v) {
    v += __int_as_float(__builtin_amdgcn_update_dpp(0, __float_as_int(v), 0x121, 0xf, 0xf, true));
    v += __int_as_float(__builtin_amdgcn_update_dpp(0, __float_as_int(v), 0x122, 0xf, 0xf, true));
    v += __int_as_float(__builtin_amdgcn_update_dpp(0, __float_as_int(v), 0x124, 0xf, 0xf, true));
    v += __int_as_float(__builtin_amdgcn_update_dpp(0, __float_as_int(v), 0x128, 0xf, 0xf, true));
    return v;
}
__device__ __forceinline__ float att_dot(float4 v, float4 xr4, float4 a1, float4 a2) {
    float e = 0.f, z;
    z = v.x + xr4.x; e = fmaf(z > 0.f ? a1.x : a2.x, z, e);
    z = v.y + xr4.y; e = fmaf(z > 0.f ? a1.y : a2.y, z, e);
    z = v.z + xr4.z; e = fmaf(z > 0.f ? a1.z : a2.z, z, e);
    z = v.w + xr4.w; e = fmaf(z > 0.f ? a1.w : a2.w, z, e);
    return e;
}

__global__ __launch_bounds__(256) void gat_aggregate(
    const unsigned short* __restrict__ xlr, const float* __restrict__ att,
    const int* __restrict__ row_ptr, const int* __restrict__ esrc,
    const float* __restrict__ bias, float* __restrict__ out, int n)
{
    const int lane = threadIdx.x & 63;
    const int node = __builtin_amdgcn_readfirstlane(blockIdx.x * 4 + (threadIdx.x >> 6));
    if (node >= n) return;
    const int c4 = lane * 4;

    const float LOG2E = 1.4426950408889634f;
    float4 a1 = *(const float4*)(att + c4);
    a1.x *= LOG2E; a1.y *= LOG2E; a1.z *= LOG2E; a1.w *= LOG2E;
    float4 a2 = make_float4(0.2f * a1.x, 0.2f * a1.y, 0.2f * a1.z, 0.2f * a1.w);
    const float4 xr4 = b2f4(*(const ushort4*)(xlr + (size_t)node * 512 + 256 + c4));

    // self loop first
    float4 xv = b2f4(*(const ushort4*)(xlr + (size_t)node * 512 + c4));
    float m = red16(att_dot(xv, xr4, a1, a2));
    float s = 1.f;
    float4 acc = xv;

    int t = row_ptr[node];
    const int end = row_ptr[node + 1];
    ushort4 nu;
    if (t < end) nu = *(const ushort4*)(xlr + (size_t)esrc[t] * 512 + c4);
    while (t < end) {
        float4 v = b2f4(nu);
        ++t;
        if (t < end) nu = *(const ushort4*)(xlr + (size_t)esrc[t] * 512 + c4);
        float e = red16(att_dot(v, xr4, a1, a2));
        float mn = fmaxf(m, e);
        float cs = __builtin_amdgcn_exp2f(m - mn);
        float w  = __builtin_amdgcn_exp2f(e - mn);
        s = fmaf(s, cs, w);
        acc.x = fmaf(acc.x, cs, w * v.x);
        acc.y = fmaf(acc.y, cs, w * v.y);
        acc.z = fmaf(acc.z, cs, w * v.z);
        acc.w = fmaf(acc.w, cs, w * v.w);
        m = mn;
    }

    const float inv = 1.f / (s + 1e-16f);
    float4 b4 = *(const float4*)(bias + c4);
    float4 o;
    o.x = fmaf(acc.x, inv, b4.x);
    o.y = fmaf(acc.y, inv, b4.y);
    o.z = fmaf(acc.z, inv, b4.z);
    o.w = fmaf(acc.w, inv, b4.w);
    *(float4*)(out + (size_t)node * 256 + c4) = o;
}

// ------------------------------- GraphNorm ---------------------------------
__global__ __launch_bounds__(256) void colstats(
    const float* __restrict__ x, int n,
    float* __restrict__ sum, float* __restrict__ sumsq)
{
    const int c = threadIdx.x;
    float s = 0.f, q = 0.f;
    for (int r = blockIdx.x; r < n; r += gridDim.x) {
        float v = x[(size_t)r * 256 + c];
        s += v;
        q = fmaf(v, v, q);
    }
    atomicAdd(&sum[c], s);
    atomicAdd(&sumsq[c], q);
}
__global__ void norm_finalize(const float* __restrict__ sum, const float* __restrict__ sumsq,
                              const float* __restrict__ w, const float* __restrict__ b,
                              const float* __restrict__ ms,
                              float* __restrict__ a, float* __restrict__ c2, float invn)
{
    int i = threadIdx.x;
    float mean = sum[i] * invn;
    float ex2 = sumsq[i] * invn;
    float m = ms[i];
    float var = ex2 - 2.f * m * mean * mean + m * m * mean * mean;
    float av = w[i] * rsqrtf(var + 1e-5f);
    a[i] = av;
    c2[i] = b[i] - av * m * mean;
}
// normalize + relu + cast to bf16 (GEMM input for the next stage)
__global__ void norm_apply_cast(const float* __restrict__ x, const float* __restrict__ a,
                                const float* __restrict__ c2,
                                unsigned short* __restrict__ out, int n4)
{
    int i = blockIdx.x * 256 + threadIdx.x;
    if (i >= n4) return;
    float4 v = ((const float4*)x)[i];
    int base = (i * 4) & 255;
    ushort4 o;
    o.x = f2b(fmaxf(fmaf(a[base + 0], v.x, c2[base + 0]), 0.f));
    o.y = f2b(fmaxf(fmaf(a[base + 1], v.y, c2[base + 1]), 0.f));
    o.z = f2b(fmaxf(fmaf(a[base + 2], v.z, c2[base + 2]), 0.f));
    o.w = f2b(fmaxf(fmaf(a[base + 3], v.w, c2[base + 3]), 0.f));
    ((ushort4*)out)[i] = o;
}

// ---------------------------------- lin2 -----------------------------------
__global__ void lin2_kernel(const unsigned short* __restrict__ h, const float* __restrict__ w,
                            const float* __restrict__ b, float* __restrict__ out, int n)
{
    int i = blockIdx.x * 256 + threadIdx.x;
    if (i >= n) return;
    float a0 = b[0], a1 = b[1];
    const unsigned short* hr = h + (size_t)i * 64;
    #pragma unroll
    for (int k = 0; k < 64; ++k) {
        float v = __uint_as_float(((unsigned)hr[k]) << 16);
        a0 = fmaf(v, w[k * 2 + 0], a0);
        a1 = fmaf(v, w[k * 2 + 1], a1);
    }
    out[i * 2 + 0] = a0;
    out[i * 2 + 1] = a1;
}

// ---------------------------------------------------------------------------
extern "C" void kernel_launch(void* const* d_in, const int* in_sizes, int n_in,
                              void* d_out, int out_size, void* d_ws, size_t ws_size,
                              hipStream_t stream)
{
    const float* x      = (const float*)d_in[0];
    const int*   eidx   = (const int*)d_in[1];
    const float* c0_wl  = (const float*)d_in[2];
    const float* c0_bl  = (const float*)d_in[3];
    const float* c0_wr  = (const float*)d_in[4];
    const float* c0_br  = (const float*)d_in[5];
    const float* c0_att = (const float*)d_in[6];
    const float* c0_bias= (const float*)d_in[7];
    const float* c1_wl  = (const float*)d_in[8];
    const float* c1_bl  = (const float*)d_in[9];
    const float* c1_wr  = (const float*)d_in[10];
    const float* c1_br  = (const float*)d_in[11];
    const float* c1_att = (const float*)d_in[12];
    const float* c1_bias= (const float*)d_in[13];
    const float* gn0_w  = (const float*)d_in[14];
    const float* gn0_b  = (const float*)d_in[15];
    const float* gn0_ms = (const float*)d_in[16];
    const float* gn1_w  = (const float*)d_in[17];
    const float* gn1_b  = (const float*)d_in[18];
    const float* gn1_ms = (const float*)d_in[19];
    const float* lin0_w = (const float*)d_in[20];
    const float* lin0_b = (const float*)d_in[21];
    const float* lin1_w = (const float*)d_in[22];
    const float* lin1_b = (const float*)d_in[23];
    const float* lin2_w = (const float*)d_in[24];
    const float* lin2_b = (const float*)d_in[25];

    const int n = in_sizes[0] / 128;   // 50000
    const int E = in_sizes[1] / 2;     // 800000
    const int* src = eidx;
    const int* dst = eidx + E;

    char* wsp = (char*)d_ws;
    size_t off = 0;
    auto alloc = [&](size_t bytes) -> void* {
        void* p = wsp + off;
        off = (off + bytes + 255) & ~(size_t)255;
        return p;
    };
    unsigned short* xbf  = (unsigned short*)alloc((size_t)n * 128 * 2);  // x bf16
    unsigned short* xlr  = (unsigned short*)alloc((size_t)n * 512 * 2);  // [xl|xr] bf16
    float*          hb   = (float*)alloc((size_t)n * 256 * 4);           // aggregate out fp32
    unsigned short* hbb  = (unsigned short*)alloc((size_t)n * 256 * 2);  // normed bf16
    unsigned short* mbuf = (unsigned short*)alloc((size_t)n * 64 * 2);
    unsigned short* mbuf2= (unsigned short*)alloc((size_t)n * 64 * 2);
    unsigned short* Wt0  = (unsigned short*)alloc((size_t)512 * 128 * 2);
    unsigned short* Wt1  = (unsigned short*)alloc((size_t)512 * 256 * 2);
    unsigned short* Lt0  = (unsigned short*)alloc((size_t)64 * 256 * 2);
    unsigned short* Lt1  = (unsigned short*)alloc((size_t)64 * 64 * 2);
    int*   esrc    = (int*)alloc((size_t)E * 4);
    int*   row_ptr = (int*)alloc((size_t)(n + 1) * 4);
    int*   cursor  = (int*)alloc((size_t)n * 4);
    int*   hist    = (int*)alloc((size_t)n * 4);
    int*   bsum    = (int*)alloc((size_t)256 * 4);
    float* s_sum   = (float*)alloc(256 * 4);
    float* s_sq    = (float*)alloc(256 * 4);
    float* s_a     = (float*)alloc(256 * 4);
    float* s_c     = (float*)alloc(256 * 4);

    // ---- prep: casts + weight transposes ----
    cast_bf16<<<(n * 128 / 4 + 255) / 256, 256, 0, stream>>>(x, xbf, n * 128 / 4);
    transpose_cast<<<(128 * 256 + 255) / 256, 256, 0, stream>>>(c0_wl, Wt0, 128, 256);
    transpose_cast<<<(128 * 256 + 255) / 256, 256, 0, stream>>>(c0_wr, Wt0 + 256 * 128, 128, 256);
    transpose_cast<<<(256 * 256 + 255) / 256, 256, 0, stream>>>(c1_wl, Wt1, 256, 256);
    transpose_cast<<<(256 * 256 + 255) / 256, 256, 0, stream>>>(c1_wr, Wt1 + 256 * 256, 256, 256);
    transpose_cast<<<(256 * 64 + 255) / 256, 256, 0, stream>>>(lin0_w, Lt0, 256, 64);
    transpose_cast<<<(64 * 64 + 255) / 256, 256, 0, stream>>>(lin1_w, Lt1, 64, 64);

    // ---- CSR by dst (parallel scan) ----
    const int nblk = (n + 255) / 256;   // 196 <= 256
    zero_i32<<<(n + 255) / 256, 256, 0, stream>>>(hist, n);
    hist_kernel<<<(E + 255) / 256, 256, 0, stream>>>(dst, E, hist);
    blk_sum_kernel<<<nblk, 256, 0, stream>>>(hist, n, bsum);
    bsum_scan_kernel<<<1, 256, 0, stream>>>(bsum, nblk, row_ptr, n);
    final_scan_kernel<<<nblk, 256, 0, stream>>>(hist, bsum, n, row_ptr, cursor);
    scatter_kernel<<<(E + 255) / 256, 256, 0, stream>>>(src, dst, E, cursor, esrc);

    const int mt = (n + 127) / 128;
    const int gagg = (n + 3) / 4;

    // ---- conv0: fused [xl|xr] GEMM + aggregate + norm ----
    mfma_gemm<false><<<dim3(8, mt), 256, 0, stream>>>(xbf, Wt0, c0_bl, c0_br, 256, xlr, n, 512, 128);
    gat_aggregate<<<gagg, 256, 0, stream>>>(xlr, c0_att, row_ptr, esrc, c0_bias, hb, n);
    zero_f32<<<2, 256, 0, stream>>>(s_sum, 512);   // s_sum,s_sq contiguous
    colstats<<<512, 256, 0, stream>>>(hb, n, s_sum, s_sq);
    norm_finalize<<<1, 256, 0, stream>>>(s_sum, s_sq, gn0_w, gn0_b, gn0_ms, s_a, s_c, 1.f / n);
    norm_apply_cast<<<((n * 64) + 255) / 256, 256, 0, stream>>>(hb, s_a, s_c, hbb, n * 64);

    // ---- conv1 ----
    mfma_gemm<false><<<dim3(8, mt), 256, 0, stream>>>(hbb, Wt1, c1_bl, c1_br, 256, xlr, n, 512, 256);
    gat_aggregate<<<gagg, 256, 0, stream>>>(xlr, c1_att, row_ptr, esrc, c1_bias, hb, n);
    zero_f32<<<2, 256, 0, stream>>>(s_sum, 512);
    colstats<<<512, 256, 0, stream>>>(hb, n, s_sum, s_sq);
    norm_finalize<<<1, 256, 0, stream>>>(s_sum, s_sq, gn1_w, gn1_b, gn1_ms, s_a, s_c, 1.f / n);
    norm_apply_cast<<<((n * 64) + 255) / 256, 256, 0, stream>>>(hb, s_a, s_c, hbb, n * 64);

    // ---- MLP ----
    mfma_gemm<true><<<dim3(1, mt), 256, 0, stream>>>(hbb, Lt0, lin0_b, lin0_b, 64, mbuf, n, 64, 256);
    mfma_gemm<true><<<dim3(1, mt), 256, 0, stream>>>(mbuf, Lt1, lin1_b, lin1_b, 64, mbuf2, n, 64, 64);
    lin2_kernel<<<(n + 255) / 256, 256, 0, stream>>>(mbuf2, lin2_w, lin2_b, (float*)d_out, n);
}

// Round 6
// 505.609 us; speedup vs baseline: 2.0981x; 1.0577x over previous
//
#include <hip/hip_runtime.h>
#include <hip/hip_bf16.h>

// ---------------------------------------------------------------------------
// GATv2 (2 conv + GraphNorm + MLP) on MI355X.
// Round 6: GEMM rework — XCD-bijective chunked swizzle with M-fast ordering
// (A stays in each XCD's L2, fetched from HBM once) + operand-swapped MFMA
// so each lane owns 4 consecutive C columns -> 8B contiguous stores (no RMW).
// Aggregate / norm / scan unchanged from round 5.
// ---------------------------------------------------------------------------

typedef __bf16 bf16x8 __attribute__((ext_vector_type(8)));
typedef float  f32x4  __attribute__((ext_vector_type(4)));

__device__ __forceinline__ unsigned short f2b(float f) {   // RNE f32->bf16
    unsigned u = __float_as_uint(f);
    return (unsigned short)((u + 0x7fffu + ((u >> 16) & 1u)) >> 16);
}
__device__ __forceinline__ float4 b2f4(ushort4 u) {        // exact bf16->f32
    float4 f;
    f.x = __uint_as_float(((unsigned)u.x) << 16);
    f.y = __uint_as_float(((unsigned)u.y) << 16);
    f.z = __uint_as_float(((unsigned)u.z) << 16);
    f.w = __uint_as_float(((unsigned)u.w) << 16);
    return f;
}

// ----------------------------- prep kernels --------------------------------
__global__ void cast_bf16(const float* __restrict__ src, unsigned short* __restrict__ dst, int n4) {
    int i = blockIdx.x * 256 + threadIdx.x;
    if (i >= n4) return;
    float4 v = ((const float4*)src)[i];
    ushort4 o = { f2b(v.x), f2b(v.y), f2b(v.z), f2b(v.w) };
    ((ushort4*)dst)[i] = o;
}
// dst[n*K+k] = bf16(src[k*N+n])   (weight transpose+cast; tiny matrices)
__global__ void transpose_cast(const float* __restrict__ src, unsigned short* __restrict__ dst,
                               int K, int N) {
    int i = blockIdx.x * 256 + threadIdx.x;
    if (i >= K * N) return;
    int nn = i / K, kk = i - nn * K;
    dst[i] = f2b(src[(size_t)kk * N + nn]);
}

// ----------------------------- MFMA GEMM -----------------------------------
// C[M,N](bf16) = act(A[M,K](bf16) @ Bt[N,K]^T(bf16) + bias); K%32==0, N%64==0.
// Block: 4 waves, tile 128(M)x64(N); wave w owns rows [w*32, w*32+32).
// 1-D grid of mt*nt blocks; XCD-bijective chunk swizzle (m204) over an
// M-fast flat index: each XCD owns a contiguous M-range for all N-tiles ->
// its A chunk (~3.2MB) stays L2-resident. MFMA operands are SWAPPED
// (first = Bt fragment, second = A fragment) so each output lane holds
// 4 consecutive C columns of one row -> 8B contiguous stores.
template<bool RELU>
__global__ __launch_bounds__(256) void mfma_gemm(
    const unsigned short* __restrict__ A, const unsigned short* __restrict__ Bt,
    const float* __restrict__ bias0, const float* __restrict__ bias1, int split,
    unsigned short* __restrict__ C, int M, int N, int K, int nt)
{
    // XCD-bijective swizzle of flat block id
    const int nwg = gridDim.x;
    const int bid = blockIdx.x;
    const int q = nwg >> 3, r = nwg & 7;
    const int xcd = bid & 7, pos = bid >> 3;
    const int wgid = (xcd < r ? xcd * (q + 1) : r * (q + 1) + (xcd - r) * q) + pos;
    const int tm = wgid / nt;            // M-tile (flat is M-fast within chunk)
    const int tn = wgid - tm * nt;       // N-tile

    const int lane = threadIdx.x & 63;
    const int w = threadIdx.x >> 6;
    const int bm = tm * 128 + w * 32;
    const int bn = tn * 64;
    const int lr = lane & 15;
    const int g  = lane >> 4;
    const int lk = g * 8;

    f32x4 acc[2][4] = {};
    int r0 = bm + lr;      if (r0 >= M) r0 = M - 1;
    int r1 = bm + 16 + lr; if (r1 >= M) r1 = M - 1;
    const unsigned short* pa0 = A + (size_t)r0 * K + lk;
    const unsigned short* pa1 = A + (size_t)r1 * K + lk;
    const unsigned short* pb  = Bt + (size_t)(bn + lr) * K + lk;

    for (int k0 = 0; k0 < K; k0 += 32) {
        bf16x8 a0 = *(const bf16x8*)(pa0 + k0);
        bf16x8 a1 = *(const bf16x8*)(pa1 + k0);
        #pragma unroll
        for (int ni = 0; ni < 4; ++ni) {
            bf16x8 b = *(const bf16x8*)(pb + (size_t)ni * 16 * K + k0);
            // swapped operands: D fragment = C^T tile -> lane holds
            // C[bm+mi*16+lr][bn+ni*16+g*4 .. +3]
            acc[0][ni] = __builtin_amdgcn_mfma_f32_16x16x32_bf16(b, a0, acc[0][ni], 0, 0, 0);
            acc[1][ni] = __builtin_amdgcn_mfma_f32_16x16x32_bf16(b, a1, acc[1][ni], 0, 0, 0);
        }
    }

    #pragma unroll
    for (int ni = 0; ni < 4; ++ni) {
        const int colbase = bn + ni * 16 + g * 4;
        const float4 bv = (colbase < split)
            ? *(const float4*)(bias0 + colbase)
            : *(const float4*)(bias1 + (colbase - split));
        #pragma unroll
        for (int mi = 0; mi < 2; ++mi) {
            const int row = bm + mi * 16 + lr;
            if (row >= M) continue;
            float v0 = acc[mi][ni][0] + bv.x;
            float v1 = acc[mi][ni][1] + bv.y;
            float v2 = acc[mi][ni][2] + bv.z;
            float v3 = acc[mi][ni][3] + bv.w;
            if (RELU) {
                v0 = fmaxf(v0, 0.f); v1 = fmaxf(v1, 0.f);
                v2 = fmaxf(v2, 0.f); v3 = fmaxf(v3, 0.f);
            }
            ushort4 o = { f2b(v0), f2b(v1), f2b(v2), f2b(v3) };
            *(ushort4*)(C + (size_t)row * N + colbase) = o;
        }
    }
}

// ----------------------------- CSR build (by dst) --------------------------
__global__ void zero_i32(int* __restrict__ p, int n) {
    int i = blockIdx.x * 256 + threadIdx.x;
    if (i < n) p[i] = 0;
}
__global__ void zero_f32(float* __restrict__ p, int n) {
    int i = blockIdx.x * 256 + threadIdx.x;
    if (i < n) p[i] = 0.f;
}
__global__ void hist_kernel(const int* __restrict__ dst, int E, int* __restrict__ hist) {
    int e = blockIdx.x * 256 + threadIdx.x;
    if (e < E) atomicAdd(&hist[dst[e]], 1);
}

// 3-phase parallel exclusive scan of hist[n] -> row_ptr[n+1] (+cursor copy)
__global__ void blk_sum_kernel(const int* __restrict__ hist, int n, int* __restrict__ bsum) {
    __shared__ int lds[256];
    int t = threadIdx.x;
    int i = blockIdx.x * 256 + t;
    lds[t] = (i < n) ? hist[i] : 0;
    __syncthreads();
    for (int off = 128; off > 0; off >>= 1) {
        if (t < off) lds[t] += lds[t + off];
        __syncthreads();
    }
    if (t == 0) bsum[blockIdx.x] = lds[0];
}
__global__ void bsum_scan_kernel(int* __restrict__ bsum, int nblk,
                                 int* __restrict__ row_ptr, int n) {
    __shared__ int lds[256];
    int t = threadIdx.x;
    int v = (t < nblk) ? bsum[t] : 0;
    lds[t] = v;
    __syncthreads();
    for (int off = 1; off < 256; off <<= 1) {
        int u = (t >= off) ? lds[t - off] : 0;
        __syncthreads();
        lds[t] += u;
        __syncthreads();
    }
    if (t < nblk) bsum[t] = lds[t] - v;        // exclusive block offset
    if (t == 255) row_ptr[n] = lds[255];       // grand total
}
__global__ void final_scan_kernel(const int* __restrict__ hist, const int* __restrict__ bsum,
                                  int n, int* __restrict__ row_ptr, int* __restrict__ cursor) {
    __shared__ int lds[256];
    int t = threadIdx.x;
    int i = blockIdx.x * 256 + t;
    int v = (i < n) ? hist[i] : 0;
    lds[t] = v;
    __syncthreads();
    for (int off = 1; off < 256; off <<= 1) {
        int u = (t >= off) ? lds[t - off] : 0;
        __syncthreads();
        lds[t] += u;
        __syncthreads();
    }
    if (i < n) {
        int ex = bsum[blockIdx.x] + lds[t] - v;
        row_ptr[i] = ex;
        cursor[i] = ex;
    }
}

__global__ void scatter_kernel(const int* __restrict__ src, const int* __restrict__ dst,
                               int E, int* cursor, int* __restrict__ esrc)
{
    int e = blockIdx.x * 256 + threadIdx.x;
    if (e < E) {
        int pos = atomicAdd(&cursor[dst[e]], 1);
        esrc[pos] = src[e];
    }
}

// --------------------- fused GATv2 softmax + aggregation -------------------
// One wave per node; lane l owns channels [4l,4l+4); 16-lane DPP reduce;
// online softmax in exp2 domain. xlr is bf16 [node][512] = [xl | xr].
__device__ __forceinline__ float red16(float v) {
    v += __int_as_float(__builtin_amdgcn_update_dpp(0, __float_as_int(v), 0x121, 0xf, 0xf, true));
    v += __int_as_float(__builtin_amdgcn_update_dpp(0, __float_as_int(v), 0x122, 0xf, 0xf, true));
    v += __int_as_float(__builtin_amdgcn_update_dpp(0, __float_as_int(v), 0x124, 0xf, 0xf, true));
    v += __int_as_float(__builtin_amdgcn_update_dpp(0, __float_as_int(v), 0x128, 0xf, 0xf, true));
    return v;
}
__device__ __forceinline__ float att_dot(float4 v, float4 xr4, float4 a1, float4 a2) {
    float e = 0.f, z;
    z = v.x + xr4.x; e = fmaf(z > 0.f ? a1.x : a2.x, z, e);
    z = v.y + xr4.y; e = fmaf(z > 0.f ? a1.y : a2.y, z, e);
    z = v.z + xr4.z; e = fmaf(z > 0.f ? a1.z : a2.z, z, e);
    z = v.w + xr4.w; e = fmaf(z > 0.f ? a1.w : a2.w, z, e);
    return e;
}

__global__ __launch_bounds__(256) void gat_aggregate(
    const unsigned short* __restrict__ xlr, const float* __restrict__ att,
    const int* __restrict__ row_ptr, const int* __restrict__ esrc,
    const float* __restrict__ bias, float* __restrict__ out, int n)
{
    const int lane = threadIdx.x & 63;
    const int node = __builtin_amdgcn_readfirstlane(blockIdx.x * 4 + (threadIdx.x >> 6));
    if (node >= n) return;
    const int c4 = lane * 4;

    const float LOG2E = 1.4426950408889634f;
    float4 a1 = *(const float4*)(att + c4);
    a1.x *= LOG2E; a1.y *= LOG2E; a1.z *= LOG2E; a1.w *= LOG2E;
    float4 a2 = make_float4(0.2f * a1.x, 0.2f * a1.y, 0.2f * a1.z, 0.2f * a1.w);
    const float4 xr4 = b2f4(*(const ushort4*)(xlr + (size_t)node * 512 + 256 + c4));

    // self loop first
    float4 xv = b2f4(*(const ushort4*)(xlr + (size_t)node * 512 + c4));
    float m = red16(att_dot(xv, xr4, a1, a2));
    float s = 1.f;
    float4 acc = xv;

    int t = row_ptr[node];
    const int end = row_ptr[node + 1];
    ushort4 nu;
    if (t < end) nu = *(const ushort4*)(xlr + (size_t)esrc[t] * 512 + c4);
    while (t < end) {
        float4 v = b2f4(nu);
        ++t;
        if (t < end) nu = *(const ushort4*)(xlr + (size_t)esrc[t] * 512 + c4);
        float e = red16(att_dot(v, xr4, a1, a2));
        float mn = fmaxf(m, e);
        float cs = __builtin_amdgcn_exp2f(m - mn);
        float w  = __builtin_amdgcn_exp2f(e - mn);
        s = fmaf(s, cs, w);
        acc.x = fmaf(acc.x, cs, w * v.x);
        acc.y = fmaf(acc.y, cs, w * v.y);
        acc.z = fmaf(acc.z, cs, w * v.z);
        acc.w = fmaf(acc.w, cs, w * v.w);
        m = mn;
    }

    const float inv = 1.f / (s + 1e-16f);
    float4 b4 = *(const float4*)(bias + c4);
    float4 o;
    o.x = fmaf(acc.x, inv, b4.x);
    o.y = fmaf(acc.y, inv, b4.y);
    o.z = fmaf(acc.z, inv, b4.z);
    o.w = fmaf(acc.w, inv, b4.w);
    *(float4*)(out + (size_t)node * 256 + c4) = o;
}

// ------------------------------- GraphNorm ---------------------------------
__global__ __launch_bounds__(256) void colstats(
    const float* __restrict__ x, int n,
    float* __restrict__ sum, float* __restrict__ sumsq)
{
    const int c = threadIdx.x;
    float s = 0.f, q = 0.f;
    for (int r = blockIdx.x; r < n; r += gridDim.x) {
        float v = x[(size_t)r * 256 + c];
        s += v;
        q = fmaf(v, v, q);
    }
    atomicAdd(&sum[c], s);
    atomicAdd(&sumsq[c], q);
}
__global__ void norm_finalize(const float* __restrict__ sum, const float* __restrict__ sumsq,
                              const float* __restrict__ w, const float* __restrict__ b,
                              const float* __restrict__ ms,
                              float* __restrict__ a, float* __restrict__ c2, float invn)
{
    int i = threadIdx.x;
    float mean = sum[i] * invn;
    float ex2 = sumsq[i] * invn;
    float m = ms[i];
    float var = ex2 - 2.f * m * mean * mean + m * m * mean * mean;
    float av = w[i] * rsqrtf(var + 1e-5f);
    a[i] = av;
    c2[i] = b[i] - av * m * mean;
}
// normalize + relu + cast to bf16 (GEMM input for the next stage)
__global__ void norm_apply_cast(const float* __restrict__ x, const float* __restrict__ a,
                                const float* __restrict__ c2,
                                unsigned short* __restrict__ out, int n4)
{
    int i = blockIdx.x * 256 + threadIdx.x;
    if (i >= n4) return;
    float4 v = ((const float4*)x)[i];
    int base = (i * 4) & 255;
    ushort4 o;
    o.x = f2b(fmaxf(fmaf(a[base + 0], v.x, c2[base + 0]), 0.f));
    o.y = f2b(fmaxf(fmaf(a[base + 1], v.y, c2[base + 1]), 0.f));
    o.z = f2b(fmaxf(fmaf(a[base + 2], v.z, c2[base + 2]), 0.f));
    o.w = f2b(fmaxf(fmaf(a[base + 3], v.w, c2[base + 3]), 0.f));
    ((ushort4*)out)[i] = o;
}

// ---------------------------------- lin2 -----------------------------------
__global__ void lin2_kernel(const unsigned short* __restrict__ h, const float* __restrict__ w,
                            const float* __restrict__ b, float* __restrict__ out, int n)
{
    int i = blockIdx.x * 256 + threadIdx.x;
    if (i >= n) return;
    float a0 = b[0], a1 = b[1];
    const unsigned short* hr = h + (size_t)i * 64;
    #pragma unroll
    for (int k = 0; k < 64; ++k) {
        float v = __uint_as_float(((unsigned)hr[k]) << 16);
        a0 = fmaf(v, w[k * 2 + 0], a0);
        a1 = fmaf(v, w[k * 2 + 1], a1);
    }
    out[i * 2 + 0] = a0;
    out[i * 2 + 1] = a1;
}

// ---------------------------------------------------------------------------
extern "C" void kernel_launch(void* const* d_in, const int* in_sizes, int n_in,
                              void* d_out, int out_size, void* d_ws, size_t ws_size,
                              hipStream_t stream)
{
    const float* x      = (const float*)d_in[0];
    const int*   eidx   = (const int*)d_in[1];
    const float* c0_wl  = (const float*)d_in[2];
    const float* c0_bl  = (const float*)d_in[3];
    const float* c0_wr  = (const float*)d_in[4];
    const float* c0_br  = (const float*)d_in[5];
    const float* c0_att = (const float*)d_in[6];
    const float* c0_bias= (const float*)d_in[7];
    const float* c1_wl  = (const float*)d_in[8];
    const float* c1_bl  = (const float*)d_in[9];
    const float* c1_wr  = (const float*)d_in[10];
    const float* c1_br  = (const float*)d_in[11];
    const float* c1_att = (const float*)d_in[12];
    const float* c1_bias= (const float*)d_in[13];
    const float* gn0_w  = (const float*)d_in[14];
    const float* gn0_b  = (const float*)d_in[15];
    const float* gn0_ms = (const float*)d_in[16];
    const float* gn1_w  = (const float*)d_in[17];
    const float* gn1_b  = (const float*)d_in[18];
    const float* gn1_ms = (const float*)d_in[19];
    const float* lin0_w = (const float*)d_in[20];
    const float* lin0_b = (const float*)d_in[21];
    const float* lin1_w = (const float*)d_in[22];
    const float* lin1_b = (const float*)d_in[23];
    const float* lin2_w = (const float*)d_in[24];
    const float* lin2_b = (const float*)d_in[25];

    const int n = in_sizes[0] / 128;   // 50000
    const int E = in_sizes[1] / 2;     // 800000
    const int* src = eidx;
    const int* dst = eidx + E;

    char* wsp = (char*)d_ws;
    size_t off = 0;
    auto alloc = [&](size_t bytes) -> void* {
        void* p = wsp + off;
        off = (off + bytes + 255) & ~(size_t)255;
        return p;
    };
    unsigned short* xbf  = (unsigned short*)alloc((size_t)n * 128 * 2);  // x bf16
    unsigned short* xlr  = (unsigned short*)alloc((size_t)n * 512 * 2);  // [xl|xr] bf16
    float*          hb   = (float*)alloc((size_t)n * 256 * 4);           // aggregate out fp32
    unsigned short* hbb  = (unsigned short*)alloc((size_t)n * 256 * 2);  // normed bf16
    unsigned short* mbuf = (unsigned short*)alloc((size_t)n * 64 * 2);
    unsigned short* mbuf2= (unsigned short*)alloc((size_t)n * 64 * 2);
    unsigned short* Wt0  = (unsigned short*)alloc((size_t)512 * 128 * 2);
    unsigned short* Wt1  = (unsigned short*)alloc((size_t)512 * 256 * 2);
    unsigned short* Lt0  = (unsigned short*)alloc((size_t)64 * 256 * 2);
    unsigned short* Lt1  = (unsigned short*)alloc((size_t)64 * 64 * 2);
    int*   esrc    = (int*)alloc((size_t)E * 4);
    int*   row_ptr = (int*)alloc((size_t)(n + 1) * 4);
    int*   cursor  = (int*)alloc((size_t)n * 4);
    int*   hist    = (int*)alloc((size_t)n * 4);
    int*   bsum    = (int*)alloc((size_t)256 * 4);
    float* s_sum   = (float*)alloc(256 * 4);
    float* s_sq    = (float*)alloc(256 * 4);
    float* s_a     = (float*)alloc(256 * 4);
    float* s_c     = (float*)alloc(256 * 4);

    // ---- prep: casts + weight transposes ----
    cast_bf16<<<(n * 128 / 4 + 255) / 256, 256, 0, stream>>>(x, xbf, n * 128 / 4);
    transpose_cast<<<(128 * 256 + 255) / 256, 256, 0, stream>>>(c0_wl, Wt0, 128, 256);
    transpose_cast<<<(128 * 256 + 255) / 256, 256, 0, stream>>>(c0_wr, Wt0 + 256 * 128, 128, 256);
    transpose_cast<<<(256 * 256 + 255) / 256, 256, 0, stream>>>(c1_wl, Wt1, 256, 256);
    transpose_cast<<<(256 * 256 + 255) / 256, 256, 0, stream>>>(c1_wr, Wt1 + 256 * 256, 256, 256);
    transpose_cast<<<(256 * 64 + 255) / 256, 256, 0, stream>>>(lin0_w, Lt0, 256, 64);
    transpose_cast<<<(64 * 64 + 255) / 256, 256, 0, stream>>>(lin1_w, Lt1, 64, 64);

    // ---- CSR by dst (parallel scan) ----
    const int nblk = (n + 255) / 256;   // 196 <= 256
    zero_i32<<<(n + 255) / 256, 256, 0, stream>>>(hist, n);
    hist_kernel<<<(E + 255) / 256, 256, 0, stream>>>(dst, E, hist);
    blk_sum_kernel<<<nblk, 256, 0, stream>>>(hist, n, bsum);
    bsum_scan_kernel<<<1, 256, 0, stream>>>(bsum, nblk, row_ptr, n);
    final_scan_kernel<<<nblk, 256, 0, stream>>>(hist, bsum, n, row_ptr, cursor);
    scatter_kernel<<<(E + 255) / 256, 256, 0, stream>>>(src, dst, E, cursor, esrc);

    const int mt = (n + 127) / 128;     // 391
    const int gagg = (n + 3) / 4;

    // ---- conv0: fused [xl|xr] GEMM + aggregate + norm ----
    mfma_gemm<false><<<mt * 8, 256, 0, stream>>>(xbf, Wt0, c0_bl, c0_br, 256, xlr, n, 512, 128, 8);
    gat_aggregate<<<gagg, 256, 0, stream>>>(xlr, c0_att, row_ptr, esrc, c0_bias, hb, n);
    zero_f32<<<2, 256, 0, stream>>>(s_sum, 512);   // s_sum,s_sq contiguous
    colstats<<<512, 256, 0, stream>>>(hb, n, s_sum, s_sq);
    norm_finalize<<<1, 256, 0, stream>>>(s_sum, s_sq, gn0_w, gn0_b, gn0_ms, s_a, s_c, 1.f / n);
    norm_apply_cast<<<((n * 64) + 255) / 256, 256, 0, stream>>>(hb, s_a, s_c, hbb, n * 64);

    // ---- conv1 ----
    mfma_gemm<false><<<mt * 8, 256, 0, stream>>>(hbb, Wt1, c1_bl, c1_br, 256, xlr, n, 512, 256, 8);
    gat_aggregate<<<gagg, 256, 0, stream>>>(xlr, c1_att, row_ptr, esrc, c1_bias, hb, n);
    zero_f32<<<2, 256, 0, stream>>>(s_sum, 512);
    colstats<<<512, 256, 0, stream>>>(hb, n, s_sum, s_sq);
    norm_finalize<<<1, 256, 0, stream>>>(s_sum, s_sq, gn1_w, gn1_b, gn1_ms, s_a, s_c, 1.f / n);
    norm_apply_cast<<<((n * 64) + 255) / 256, 256, 0, stream>>>(hb, s_a, s_c, hbb, n * 64);

    // ---- MLP ----
    mfma_gemm<true><<<mt, 256, 0, stream>>>(hbb, Lt0, lin0_b, lin0_b, 64, mbuf, n, 64, 256, 1);
    mfma_gemm<true><<<mt, 256, 0, stream>>>(mbuf, Lt1, lin1_b, lin1_b, 64, mbuf2, n, 64, 64, 1);
    lin2_kernel<<<(n + 255) / 256, 256, 0, stream>>>(mbuf2, lin2_w, lin2_b, (float*)d_out, n);
}

// Round 7
// 486.247 us; speedup vs baseline: 2.1816x; 1.0398x over previous
//
#include <hip/hip_runtime.h>
#include <hip/hip_bf16.h>

// ---------------------------------------------------------------------------
// GATv2 (2 conv + GraphNorm + MLP) on MI355X.
// Round 7: GEMM latency fix — 256Mx64N tile (wave = 64Mx64N, 16 MFMA : 8 loads
// per K-step), compile-time K + full unroll for deep load pipelining, B slice
// shared by all 4 waves (L1). XCD swizzle + swapped-operand epilogue kept.
// Aggregate / norm / scan unchanged from round 6.
// ---------------------------------------------------------------------------

typedef __bf16 bf16x8 __attribute__((ext_vector_type(8)));
typedef float  f32x4  __attribute__((ext_vector_type(4)));

__device__ __forceinline__ unsigned short f2b(float f) {   // RNE f32->bf16
    unsigned u = __float_as_uint(f);
    return (unsigned short)((u + 0x7fffu + ((u >> 16) & 1u)) >> 16);
}
__device__ __forceinline__ float4 b2f4(ushort4 u) {        // exact bf16->f32
    float4 f;
    f.x = __uint_as_float(((unsigned)u.x) << 16);
    f.y = __uint_as_float(((unsigned)u.y) << 16);
    f.z = __uint_as_float(((unsigned)u.z) << 16);
    f.w = __uint_as_float(((unsigned)u.w) << 16);
    return f;
}

// ----------------------------- prep kernels --------------------------------
__global__ void cast_bf16(const float* __restrict__ src, unsigned short* __restrict__ dst, int n4) {
    int i = blockIdx.x * 256 + threadIdx.x;
    if (i >= n4) return;
    float4 v = ((const float4*)src)[i];
    ushort4 o = { f2b(v.x), f2b(v.y), f2b(v.z), f2b(v.w) };
    ((ushort4*)dst)[i] = o;
}
// dst[n*K+k] = bf16(src[k*N+n])   (weight transpose+cast; tiny matrices)
__global__ void transpose_cast(const float* __restrict__ src, unsigned short* __restrict__ dst,
                               int K, int N) {
    int i = blockIdx.x * 256 + threadIdx.x;
    if (i >= K * N) return;
    int nn = i / K, kk = i - nn * K;
    dst[i] = f2b(src[(size_t)kk * N + nn]);
}

// ----------------------------- MFMA GEMM -----------------------------------
// C[M,N](bf16) = act(A[M,K](bf16) @ Bt[N,K]^T(bf16) + bias); K compile-time.
// Block: 4 waves, tile 256(M)x64(N); wave w owns rows [w*64, w*64+64).
// All waves share the same 64-row Bt slice (32KB at K=256 -> L1-resident).
// 1-D grid, XCD-bijective chunk swizzle, M-fast flat index (A chunk stays in
// the XCD's L2). Swapped-operand MFMA: lane holds 4 consecutive C columns.
template<int K, bool RELU>
__global__ __launch_bounds__(256) void mfma_gemm(
    const unsigned short* __restrict__ A, const unsigned short* __restrict__ Bt,
    const float* __restrict__ bias0, const float* __restrict__ bias1, int split,
    unsigned short* __restrict__ C, int M, int N, int nt)
{
    // XCD-bijective swizzle of flat block id (m204 formula)
    const int nwg = gridDim.x;
    const int bid = blockIdx.x;
    const int q = nwg >> 3, r = nwg & 7;
    const int xcd = bid & 7, pos = bid >> 3;
    const int wgid = (xcd < r ? xcd * (q + 1) : r * (q + 1) + (xcd - r) * q) + pos;
    const int tm = wgid / nt;            // M-tile (flat is M-fast within chunk)
    const int tn = wgid - tm * nt;       // N-tile

    const int lane = threadIdx.x & 63;
    const int w = threadIdx.x >> 6;
    const int bm = tm * 256 + w * 64;
    const int bn = tn * 64;
    const int lr = lane & 15;
    const int g  = lane >> 4;
    const int lk = g * 8;

    f32x4 acc[4][4] = {};
    const unsigned short* pa[4];
    #pragma unroll
    for (int mi = 0; mi < 4; ++mi) {
        int rr = bm + mi * 16 + lr;
        if (rr >= M) rr = M - 1;         // clamp (writes are guarded)
        pa[mi] = A + (size_t)rr * K + lk;
    }
    const unsigned short* pb = Bt + (size_t)(bn + lr) * K + lk;

    #pragma unroll
    for (int k0 = 0; k0 < K; k0 += 32) {
        bf16x8 bfr[4], afr[4];
        #pragma unroll
        for (int ni = 0; ni < 4; ++ni)
            bfr[ni] = *(const bf16x8*)(pb + (size_t)ni * 16 * K + k0);
        #pragma unroll
        for (int mi = 0; mi < 4; ++mi)
            afr[mi] = *(const bf16x8*)(pa[mi] + k0);
        #pragma unroll
        for (int mi = 0; mi < 4; ++mi)
            #pragma unroll
            for (int ni = 0; ni < 4; ++ni)
                acc[mi][ni] = __builtin_amdgcn_mfma_f32_16x16x32_bf16(
                    bfr[ni], afr[mi], acc[mi][ni], 0, 0, 0);
    }

    // epilogue: lane holds C[bm+mi*16+lr][bn+ni*16+g*4 .. +3]
    #pragma unroll
    for (int ni = 0; ni < 4; ++ni) {
        const int colbase = bn + ni * 16 + g * 4;
        const float4 bv = (colbase < split)
            ? *(const float4*)(bias0 + colbase)
            : *(const float4*)(bias1 + (colbase - split));
        #pragma unroll
        for (int mi = 0; mi < 4; ++mi) {
            const int row = bm + mi * 16 + lr;
            if (row >= M) continue;
            float v0 = acc[mi][ni][0] + bv.x;
            float v1 = acc[mi][ni][1] + bv.y;
            float v2 = acc[mi][ni][2] + bv.z;
            float v3 = acc[mi][ni][3] + bv.w;
            if (RELU) {
                v0 = fmaxf(v0, 0.f); v1 = fmaxf(v1, 0.f);
                v2 = fmaxf(v2, 0.f); v3 = fmaxf(v3, 0.f);
            }
            ushort4 o = { f2b(v0), f2b(v1), f2b(v2), f2b(v3) };
            *(ushort4*)(C + (size_t)row * N + colbase) = o;
        }
    }
}

// ----------------------------- CSR build (by dst) --------------------------
__global__ void zero_i32(int* __restrict__ p, int n) {
    int i = blockIdx.x * 256 + threadIdx.x;
    if (i < n) p[i] = 0;
}
__global__ void zero_f32(float* __restrict__ p, int n) {
    int i = blockIdx.x * 256 + threadIdx.x;
    if (i < n) p[i] = 0.f;
}
__global__ void hist_kernel(const int* __restrict__ dst, int E, int* __restrict__ hist) {
    int e = blockIdx.x * 256 + threadIdx.x;
    if (e < E) atomicAdd(&hist[dst[e]], 1);
}

// 3-phase parallel exclusive scan of hist[n] -> row_ptr[n+1] (+cursor copy)
__global__ void blk_sum_kernel(const int* __restrict__ hist, int n, int* __restrict__ bsum) {
    __shared__ int lds[256];
    int t = threadIdx.x;
    int i = blockIdx.x * 256 + t;
    lds[t] = (i < n) ? hist[i] : 0;
    __syncthreads();
    for (int off = 128; off > 0; off >>= 1) {
        if (t < off) lds[t] += lds[t + off];
        __syncthreads();
    }
    if (t == 0) bsum[blockIdx.x] = lds[0];
}
__global__ void bsum_scan_kernel(int* __restrict__ bsum, int nblk,
                                 int* __restrict__ row_ptr, int n) {
    __shared__ int lds[256];
    int t = threadIdx.x;
    int v = (t < nblk) ? bsum[t] : 0;
    lds[t] = v;
    __syncthreads();
    for (int off = 1; off < 256; off <<= 1) {
        int u = (t >= off) ? lds[t - off] : 0;
        __syncthreads();
        lds[t] += u;
        __syncthreads();
    }
    if (t < nblk) bsum[t] = lds[t] - v;        // exclusive block offset
    if (t == 255) row_ptr[n] = lds[255];       // grand total
}
__global__ void final_scan_kernel(const int* __restrict__ hist, const int* __restrict__ bsum,
                                  int n, int* __restrict__ row_ptr, int* __restrict__ cursor) {
    __shared__ int lds[256];
    int t = threadIdx.x;
    int i = blockIdx.x * 256 + t;
    int v = (i < n) ? hist[i] : 0;
    lds[t] = v;
    __syncthreads();
    for (int off = 1; off < 256; off <<= 1) {
        int u = (t >= off) ? lds[t - off] : 0;
        __syncthreads();
        lds[t] += u;
        __syncthreads();
    }
    if (i < n) {
        int ex = bsum[blockIdx.x] + lds[t] - v;
        row_ptr[i] = ex;
        cursor[i] = ex;
    }
}

__global__ void scatter_kernel(const int* __restrict__ src, const int* __restrict__ dst,
                               int E, int* cursor, int* __restrict__ esrc)
{
    int e = blockIdx.x * 256 + threadIdx.x;
    if (e < E) {
        int pos = atomicAdd(&cursor[dst[e]], 1);
        esrc[pos] = src[e];
    }
}

// --------------------- fused GATv2 softmax + aggregation -------------------
// One wave per node; lane l owns channels [4l,4l+4); 16-lane DPP reduce;
// online softmax in exp2 domain. xlr is bf16 [node][512] = [xl | xr].
__device__ __forceinline__ float red16(float v) {
    v += __int_as_float(__builtin_amdgcn_update_dpp(0, __float_as_int(v), 0x121, 0xf, 0xf, true));
    v += __int_as_float(__builtin_amdgcn_update_dpp(0, __float_as_int(v), 0x122, 0xf, 0xf, true));
    v += __int_as_float(__builtin_amdgcn_update_dpp(0, __float_as_int(v), 0x124, 0xf, 0xf, true));
    v += __int_as_float(__builtin_amdgcn_update_dpp(0, __float_as_int(v), 0x128, 0xf, 0xf, true));
    return v;
}
__device__ __forceinline__ float att_dot(float4 v, float4 xr4, float4 a1, float4 a2) {
    float e = 0.f, z;
    z = v.x + xr4.x; e = fmaf(z > 0.f ? a1.x : a2.x, z, e);
    z = v.y + xr4.y; e = fmaf(z > 0.f ? a1.y : a2.y, z, e);
    z = v.z + xr4.z; e = fmaf(z > 0.f ? a1.z : a2.z, z, e);
    z = v.w + xr4.w; e = fmaf(z > 0.f ? a1.w : a2.w, z, e);
    return e;
}

__global__ __launch_bounds__(256) void gat_aggregate(
    const unsigned short* __restrict__ xlr, const float* __restrict__ att,
    const int* __restrict__ row_ptr, const int* __restrict__ esrc,
    const float* __restrict__ bias, float* __restrict__ out, int n)
{
    const int lane = threadIdx.x & 63;
    const int node = __builtin_amdgcn_readfirstlane(blockIdx.x * 4 + (threadIdx.x >> 6));
    if (node >= n) return;
    const int c4 = lane * 4;

    const float LOG2E = 1.4426950408889634f;
    float4 a1 = *(const float4*)(att + c4);
    a1.x *= LOG2E; a1.y *= LOG2E; a1.z *= LOG2E; a1.w *= LOG2E;
    float4 a2 = make_float4(0.2f * a1.x, 0.2f * a1.y, 0.2f * a1.z, 0.2f * a1.w);
    const float4 xr4 = b2f4(*(const ushort4*)(xlr + (size_t)node * 512 + 256 + c4));

    // self loop first
    float4 xv = b2f4(*(const ushort4*)(xlr + (size_t)node * 512 + c4));
    float m = red16(att_dot(xv, xr4, a1, a2));
    float s = 1.f;
    float4 acc = xv;

    int t = row_ptr[node];
    const int end = row_ptr[node + 1];
    ushort4 nu;
    if (t < end) nu = *(const ushort4*)(xlr + (size_t)esrc[t] * 512 + c4);
    while (t < end) {
        float4 v = b2f4(nu);
        ++t;
        if (t < end) nu = *(const ushort4*)(xlr + (size_t)esrc[t] * 512 + c4);
        float e = red16(att_dot(v, xr4, a1, a2));
        float mn = fmaxf(m, e);
        float cs = __builtin_amdgcn_exp2f(m - mn);
        float w  = __builtin_amdgcn_exp2f(e - mn);
        s = fmaf(s, cs, w);
        acc.x = fmaf(acc.x, cs, w * v.x);
        acc.y = fmaf(acc.y, cs, w * v.y);
        acc.z = fmaf(acc.z, cs, w * v.z);
        acc.w = fmaf(acc.w, cs, w * v.w);
        m = mn;
    }

    const float inv = 1.f / (s + 1e-16f);
    float4 b4 = *(const float4*)(bias + c4);
    float4 o;
    o.x = fmaf(acc.x, inv, b4.x);
    o.y = fmaf(acc.y, inv, b4.y);
    o.z = fmaf(acc.z, inv, b4.z);
    o.w = fmaf(acc.w, inv, b4.w);
    *(float4*)(out + (size_t)node * 256 + c4) = o;
}

// ------------------------------- GraphNorm ---------------------------------
__global__ __launch_bounds__(256) void colstats(
    const float* __restrict__ x, int n,
    float* __restrict__ sum, float* __restrict__ sumsq)
{
    const int c = threadIdx.x;
    float s = 0.f, q = 0.f;
    for (int r = blockIdx.x; r < n; r += gridDim.x) {
        float v = x[(size_t)r * 256 + c];
        s += v;
        q = fmaf(v, v, q);
    }
    atomicAdd(&sum[c], s);
    atomicAdd(&sumsq[c], q);
}
__global__ void norm_finalize(const float* __restrict__ sum, const float* __restrict__ sumsq,
                              const float* __restrict__ w, const float* __restrict__ b,
                              const float* __restrict__ ms,
                              float* __restrict__ a, float* __restrict__ c2, float invn)
{
    int i = threadIdx.x;
    float mean = sum[i] * invn;
    float ex2 = sumsq[i] * invn;
    float m = ms[i];
    float var = ex2 - 2.f * m * mean * mean + m * m * mean * mean;
    float av = w[i] * rsqrtf(var + 1e-5f);
    a[i] = av;
    c2[i] = b[i] - av * m * mean;
}
// normalize + relu + cast to bf16 (GEMM input for the next stage)
__global__ void norm_apply_cast(const float* __restrict__ x, const float* __restrict__ a,
                                const float* __restrict__ c2,
                                unsigned short* __restrict__ out, int n4)
{
    int i = blockIdx.x * 256 + threadIdx.x;
    if (i >= n4) return;
    float4 v = ((const float4*)x)[i];
    int base = (i * 4) & 255;
    ushort4 o;
    o.x = f2b(fmaxf(fmaf(a[base + 0], v.x, c2[base + 0]), 0.f));
    o.y = f2b(fmaxf(fmaf(a[base + 1], v.y, c2[base + 1]), 0.f));
    o.z = f2b(fmaxf(fmaf(a[base + 2], v.z, c2[base + 2]), 0.f));
    o.w = f2b(fmaxf(fmaf(a[base + 3], v.w, c2[base + 3]), 0.f));
    ((ushort4*)out)[i] = o;
}

// ---------------------------------- lin2 -----------------------------------
__global__ void lin2_kernel(const unsigned short* __restrict__ h, const float* __restrict__ w,
                            const float* __restrict__ b, float* __restrict__ out, int n)
{
    int i = blockIdx.x * 256 + threadIdx.x;
    if (i >= n) return;
    float a0 = b[0], a1 = b[1];
    const unsigned short* hr = h + (size_t)i * 64;
    #pragma unroll
    for (int k = 0; k < 64; ++k) {
        float v = __uint_as_float(((unsigned)hr[k]) << 16);
        a0 = fmaf(v, w[k * 2 + 0], a0);
        a1 = fmaf(v, w[k * 2 + 1], a1);
    }
    out[i * 2 + 0] = a0;
    out[i * 2 + 1] = a1;
}

// ---------------------------------------------------------------------------
extern "C" void kernel_launch(void* const* d_in, const int* in_sizes, int n_in,
                              void* d_out, int out_size, void* d_ws, size_t ws_size,
                              hipStream_t stream)
{
    const float* x      = (const float*)d_in[0];
    const int*   eidx   = (const int*)d_in[1];
    const float* c0_wl  = (const float*)d_in[2];
    const float* c0_bl  = (const float*)d_in[3];
    const float* c0_wr  = (const float*)d_in[4];
    const float* c0_br  = (const float*)d_in[5];
    const float* c0_att = (const float*)d_in[6];
    const float* c0_bias= (const float*)d_in[7];
    const float* c1_wl  = (const float*)d_in[8];
    const float* c1_bl  = (const float*)d_in[9];
    const float* c1_wr  = (const float*)d_in[10];
    const float* c1_br  = (const float*)d_in[11];
    const float* c1_att = (const float*)d_in[12];
    const float* c1_bias= (const float*)d_in[13];
    const float* gn0_w  = (const float*)d_in[14];
    const float* gn0_b  = (const float*)d_in[15];
    const float* gn0_ms = (const float*)d_in[16];
    const float* gn1_w  = (const float*)d_in[17];
    const float* gn1_b  = (const float*)d_in[18];
    const float* gn1_ms = (const float*)d_in[19];
    const float* lin0_w = (const float*)d_in[20];
    const float* lin0_b = (const float*)d_in[21];
    const float* lin1_w = (const float*)d_in[22];
    const float* lin1_b = (const float*)d_in[23];
    const float* lin2_w = (const float*)d_in[24];
    const float* lin2_b = (const float*)d_in[25];

    const int n = in_sizes[0] / 128;   // 50000
    const int E = in_sizes[1] / 2;     // 800000
    const int* src = eidx;
    const int* dst = eidx + E;

    char* wsp = (char*)d_ws;
    size_t off = 0;
    auto alloc = [&](size_t bytes) -> void* {
        void* p = wsp + off;
        off = (off + bytes + 255) & ~(size_t)255;
        return p;
    };
    unsigned short* xbf  = (unsigned short*)alloc((size_t)n * 128 * 2);  // x bf16
    unsigned short* xlr  = (unsigned short*)alloc((size_t)n * 512 * 2);  // [xl|xr] bf16
    float*          hb   = (float*)alloc((size_t)n * 256 * 4);           // aggregate out fp32
    unsigned short* hbb  = (unsigned short*)alloc((size_t)n * 256 * 2);  // normed bf16
    unsigned short* mbuf = (unsigned short*)alloc((size_t)n * 64 * 2);
    unsigned short* mbuf2= (unsigned short*)alloc((size_t)n * 64 * 2);
    unsigned short* Wt0  = (unsigned short*)alloc((size_t)512 * 128 * 2);
    unsigned short* Wt1  = (unsigned short*)alloc((size_t)512 * 256 * 2);
    unsigned short* Lt0  = (unsigned short*)alloc((size_t)64 * 256 * 2);
    unsigned short* Lt1  = (unsigned short*)alloc((size_t)64 * 64 * 2);
    int*   esrc    = (int*)alloc((size_t)E * 4);
    int*   row_ptr = (int*)alloc((size_t)(n + 1) * 4);
    int*   cursor  = (int*)alloc((size_t)n * 4);
    int*   hist    = (int*)alloc((size_t)n * 4);
    int*   bsum    = (int*)alloc((size_t)256 * 4);
    float* s_sum   = (float*)alloc(256 * 4);
    float* s_sq    = (float*)alloc(256 * 4);
    float* s_a     = (float*)alloc(256 * 4);
    float* s_c     = (float*)alloc(256 * 4);

    // ---- prep: casts + weight transposes ----
    cast_bf16<<<(n * 128 / 4 + 255) / 256, 256, 0, stream>>>(x, xbf, n * 128 / 4);
    transpose_cast<<<(128 * 256 + 255) / 256, 256, 0, stream>>>(c0_wl, Wt0, 128, 256);
    transpose_cast<<<(128 * 256 + 255) / 256, 256, 0, stream>>>(c0_wr, Wt0 + 256 * 128, 128, 256);
    transpose_cast<<<(256 * 256 + 255) / 256, 256, 0, stream>>>(c1_wl, Wt1, 256, 256);
    transpose_cast<<<(256 * 256 + 255) / 256, 256, 0, stream>>>(c1_wr, Wt1 + 256 * 256, 256, 256);
    transpose_cast<<<(256 * 64 + 255) / 256, 256, 0, stream>>>(lin0_w, Lt0, 256, 64);
    transpose_cast<<<(64 * 64 + 255) / 256, 256, 0, stream>>>(lin1_w, Lt1, 64, 64);

    // ---- CSR by dst (parallel scan) ----
    const int nblk = (n + 255) / 256;   // 196 <= 256
    zero_i32<<<(n + 255) / 256, 256, 0, stream>>>(hist, n);
    hist_kernel<<<(E + 255) / 256, 256, 0, stream>>>(dst, E, hist);
    blk_sum_kernel<<<nblk, 256, 0, stream>>>(hist, n, bsum);
    bsum_scan_kernel<<<1, 256, 0, stream>>>(bsum, nblk, row_ptr, n);
    final_scan_kernel<<<nblk, 256, 0, stream>>>(hist, bsum, n, row_ptr, cursor);
    scatter_kernel<<<(E + 255) / 256, 256, 0, stream>>>(src, dst, E, cursor, esrc);

    const int mt = (n + 255) / 256;     // 196 M-tiles (256 rows each)
    const int gagg = (n + 3) / 4;

    // ---- conv0: fused [xl|xr] GEMM + aggregate + norm ----
    mfma_gemm<128, false><<<mt * 8, 256, 0, stream>>>(xbf, Wt0, c0_bl, c0_br, 256, xlr, n, 512, 8);
    gat_aggregate<<<gagg, 256, 0, stream>>>(xlr, c0_att, row_ptr, esrc, c0_bias, hb, n);
    zero_f32<<<2, 256, 0, stream>>>(s_sum, 512);   // s_sum,s_sq contiguous
    colstats<<<512, 256, 0, stream>>>(hb, n, s_sum, s_sq);
    norm_finalize<<<1, 256, 0, stream>>>(s_sum, s_sq, gn0_w, gn0_b, gn0_ms, s_a, s_c, 1.f / n);
    norm_apply_cast<<<((n * 64) + 255) / 256, 256, 0, stream>>>(hb, s_a, s_c, hbb, n * 64);

    // ---- conv1 ----
    mfma_gemm<256, false><<<mt * 8, 256, 0, stream>>>(hbb, Wt1, c1_bl, c1_br, 256, xlr, n, 512, 8);
    gat_aggregate<<<gagg, 256, 0, stream>>>(xlr, c1_att, row_ptr, esrc, c1_bias, hb, n);
    zero_f32<<<2, 256, 0, stream>>>(s_sum, 512);
    colstats<<<512, 256, 0, stream>>>(hb, n, s_sum, s_sq);
    norm_finalize<<<1, 256, 0, stream>>>(s_sum, s_sq, gn1_w, gn1_b, gn1_ms, s_a, s_c, 1.f / n);
    norm_apply_cast<<<((n * 64) + 255) / 256, 256, 0, stream>>>(hb, s_a, s_c, hbb, n * 64);

    // ---- MLP ----
    mfma_gemm<256, true><<<mt, 256, 0, stream>>>(hbb, Lt0, lin0_b, lin0_b, 64, mbuf, n, 64, 1);
    mfma_gemm<64, true><<<mt, 256, 0, stream>>>(mbuf, Lt1, lin1_b, lin1_b, 64, mbuf2, n, 64, 1);
    lin2_kernel<<<(n + 255) / 256, 256, 0, stream>>>(mbuf2, lin2_w, lin2_b, (float*)d_out, n);
}